// Round 6
// baseline (5994.046 us; speedup 1.0000x reference)
//
#include <hip/hip_runtime.h>
#include <hip/hip_bf16.h>

// Decoder forward: B=2,T=1024,D=1024,H=16(hs=64),L=2,FF=4096,V=32000
// Outputs (FLOAT32, concat flat): logits[N,V], loss[1], maps[L,B,H,T,T], probs[N,D]
// Round 6: pipeline validated by R4/R5 on-device probes; the R1-R5 failure was
// the OUTPUT DTYPE (d_out is f32 per the reference's f32 outputs, not bf16).
#define VSZ 32000
#define DM  1024
#define TSEQ 1024
#define BB  2
#define HH  16
#define LL  2
#define FFD 4096
#define NTOK (BB*TSEQ)   // 2048

static constexpr size_t LOGITS_OFF = 0;
static constexpr size_t LOSS_OFF   = (size_t)NTOK * VSZ;                    // 65,536,000
static constexpr size_t MAPS_OFF   = LOSS_OFF + 1;
static constexpr size_t PROBS_OFF  = MAPS_OFF + (size_t)LL*BB*HH*TSEQ*TSEQ; // 132,644,865

// ---------------- reductions (block = 256 threads = 4 waves) ----------------
__device__ __forceinline__ float block_sum256(float v, float* sh) {
#pragma unroll
  for (int off = 32; off; off >>= 1) v += __shfl_down(v, off);
  int wid = threadIdx.x >> 6, lane = threadIdx.x & 63;
  if (lane == 0) sh[wid] = v;
  __syncthreads();
  v = sh[0] + sh[1] + sh[2] + sh[3];
  __syncthreads();
  return v;
}
__device__ __forceinline__ float block_max256(float v, float* sh) {
#pragma unroll
  for (int off = 32; off; off >>= 1) v = fmaxf(v, __shfl_down(v, off));
  int wid = threadIdx.x >> 6, lane = threadIdx.x & 63;
  if (lane == 0) sh[wid] = v;
  __syncthreads();
  v = fmaxf(fmaxf(sh[0], sh[1]), fmaxf(sh[2], sh[3]));
  __syncthreads();
  return v;
}

// ---------------- embedding ----------------
__global__ __launch_bounds__(256) void embed_kernel(const int* __restrict__ idx,
    const float* __restrict__ we, const float* __restrict__ pe, float* __restrict__ x) {
  int i = blockIdx.x * 256 + threadIdx.x;
  int n = i >> 10;
  int d = i & 1023;
  int t = n & (TSEQ - 1);
  x[i] = we[(size_t)idx[n] * DM + d] + pe[(size_t)t * DM + d];
}

// ---------------- LayerNorm over D=1024, one block per row ------------------
__global__ __launch_bounds__(256) void ln_kernel(const float* __restrict__ in,
    const float* __restrict__ g, const float* __restrict__ b, float* __restrict__ out) {
  __shared__ float sh[4];
  int row = blockIdx.x, tid = threadIdx.x;
  const float* xr = in + (size_t)row * DM;
  float4 v = *(const float4*)&xr[tid * 4];
  float s  = v.x + v.y + v.z + v.w;
  float s2 = v.x*v.x + v.y*v.y + v.z*v.z + v.w*v.w;
  s  = block_sum256(s, sh);
  s2 = block_sum256(s2, sh);
  float mean = s * (1.0f / DM);
  float var  = s2 * (1.0f / DM) - mean * mean;
  float inv  = rsqrtf(var + 1e-5f);
  float4 gv = *(const float4*)&g[tid * 4];
  float4 bv = *(const float4*)&b[tid * 4];
  float4 o;
  o.x = (v.x - mean) * inv * gv.x + bv.x;
  o.y = (v.y - mean) * inv * gv.y + bv.y;
  o.z = (v.z - mean) * inv * gv.z + bv.z;
  o.w = (v.w - mean) * inv * gv.w + bv.w;
  *(float4*)&out[(size_t)row * DM + tid * 4] = o;
}

// ---------------- tiled GEMM: C[M,N] = A[M,K] @ B[K,N], f32 out -------------
template<int BIAS, int RES, int RELU>
__global__ __launch_bounds__(256) void gemm_k(const float* __restrict__ A,
    const float* __restrict__ Bw, const float* __restrict__ bias,
    float* __restrict__ C, int M, int K, int Nn) {
  __shared__ float As[16][68];
  __shared__ float Bs[16][68];
  const int bm = blockIdx.y * 64, bn = blockIdx.x * 64;
  const int tid = threadIdx.x;
  const int tm = (tid >> 4) * 4, tn = (tid & 15) * 4;
  const int ra = tid >> 2, ka = (tid & 3) * 4;
  const int kb = tid >> 4, cb = (tid & 15) * 4;
  float acc[4][4] = {};
  for (int k0 = 0; k0 < K; k0 += 16) {
    float4 a4 = *(const float4*)&A[(size_t)(bm + ra) * K + k0 + ka];
    float4 b4 = *(const float4*)&Bw[(size_t)(k0 + kb) * Nn + bn + cb];
    As[ka    ][ra] = a4.x;
    As[ka + 1][ra] = a4.y;
    As[ka + 2][ra] = a4.z;
    As[ka + 3][ra] = a4.w;
    *(float4*)&Bs[kb][cb] = b4;
    __syncthreads();
#pragma unroll
    for (int kk = 0; kk < 16; ++kk) {
      float4 av = *(const float4*)&As[kk][tm];
      float4 bv = *(const float4*)&Bs[kk][tn];
      acc[0][0] += av.x * bv.x; acc[0][1] += av.x * bv.y; acc[0][2] += av.x * bv.z; acc[0][3] += av.x * bv.w;
      acc[1][0] += av.y * bv.x; acc[1][1] += av.y * bv.y; acc[1][2] += av.y * bv.z; acc[1][3] += av.y * bv.w;
      acc[2][0] += av.z * bv.x; acc[2][1] += av.z * bv.y; acc[2][2] += av.z * bv.z; acc[2][3] += av.z * bv.w;
      acc[3][0] += av.w * bv.x; acc[3][1] += av.w * bv.y; acc[3][2] += av.w * bv.z; acc[3][3] += av.w * bv.w;
    }
    __syncthreads();
  }
#pragma unroll
  for (int i = 0; i < 4; ++i) {
    size_t rowb = (size_t)(bm + tm + i) * Nn;
#pragma unroll
    for (int j = 0; j < 4; ++j) {
      int col = bn + tn + j;
      float val = acc[i][j];
      if (BIAS) val += bias[col];
      if (RES)  val += C[rowb + col];
      if (RELU) val = fmaxf(val, 0.f);
      C[rowb + col] = val;
    }
  }
}

// ---------------- attention scores + causal softmax -> maps (f32) -----------
__global__ __launch_bounds__(256) void attn_scores(const float* __restrict__ qb,
    const float* __restrict__ kb, float* __restrict__ maps_l) {
  __shared__ float qv[64];
  __shared__ float sh[4];
  const int q = blockIdx.x;
  const int bh = blockIdx.y;                 // b*H + h
  const int b = bh >> 4, h = bh & 15;
  const int tid = threadIdx.x;
  if (tid < 64) qv[tid] = qb[(size_t)(b * TSEQ + q) * DM + h * 64 + tid];
  __syncthreads();
  const float scale = 0.03125f;              // 1024^-0.5
  float s[4];
#pragma unroll
  for (int i = 0; i < 4; ++i) {
    int kp = tid + i * 256;
    if (kp <= q) {
      const float4* kv = (const float4*)&kb[(size_t)(b * TSEQ + kp) * DM + h * 64];
      float acc = 0.f;
#pragma unroll
      for (int d = 0; d < 16; ++d) {
        float4 k4 = kv[d];
        acc += qv[d*4]*k4.x + qv[d*4+1]*k4.y + qv[d*4+2]*k4.z + qv[d*4+3]*k4.w;
      }
      s[i] = acc * scale;
    } else s[i] = -1e30f;
  }
  float m = block_max256(fmaxf(fmaxf(s[0], s[1]), fmaxf(s[2], s[3])), sh);
  float e[4]; float ssum = 0.f;
#pragma unroll
  for (int i = 0; i < 4; ++i) {
    int kp = tid + i * 256;
    e[i] = (kp <= q) ? __expf(s[i] - m) : 0.f;
    ssum += e[i];
  }
  ssum = block_sum256(ssum, sh);
  float inv = 1.f / ssum;
  float* mrow = maps_l + (size_t)bh * TSEQ * TSEQ + (size_t)q * TSEQ;
#pragma unroll
  for (int i = 0; i < 4; ++i) mrow[tid + i * 256] = e[i] * inv;
}

// ---------------- att = wei @ v -> out[n, h*64+d] (f32) ---------------------
__global__ __launch_bounds__(256) void attn_av(const float* __restrict__ maps_l,
    const float* __restrict__ vb, float* __restrict__ outp) {
  const int tid = threadIdx.x;
  const int d = tid & 63, qi = tid >> 6;
  const int q = blockIdx.x * 4 + qi;
  const int bh = blockIdx.y;
  const int b = bh >> 4, h = bh & 15;
  const float* wrow = maps_l + (size_t)bh * TSEQ * TSEQ + (size_t)q * TSEQ;
  const float* vcol = vb + (size_t)b * TSEQ * DM + h * 64 + d;
  float acc = 0.f;
  for (int k = 0; k <= q; ++k)
    acc += wrow[k] * vcol[(size_t)k * DM];
  outp[(size_t)(b * TSEQ + q) * DM + h * 64 + d] = acc;
}

// ---------------- per-row CE loss from f32 logits ----------------------------
__global__ __launch_bounds__(256) void loss_rows(const float* __restrict__ logits,
    const int* __restrict__ targets, float* __restrict__ rowloss) {
  __shared__ float sh[4];
  int row = blockIdx.x, tid = threadIdx.x;
  const float* lr = logits + (size_t)row * VSZ;
  float m = -1e30f;
  for (int i = tid; i < VSZ; i += 256) m = fmaxf(m, lr[i]);
  m = block_max256(m, sh);
  float ssum = 0.f;
  for (int i = tid; i < VSZ; i += 256) ssum += __expf(lr[i] - m);
  ssum = block_sum256(ssum, sh);
  if (tid == 0)
    rowloss[row] = m + logf(ssum) - lr[targets[row]];
}
__global__ __launch_bounds__(256) void loss_reduce(const float* __restrict__ rowloss,
    float* __restrict__ out) {
  __shared__ float sh[4];
  float s = 0.f;
  for (int i = threadIdx.x; i < NTOK; i += 256) s += rowloss[i];
  s = block_sum256(s, sh);
  if (threadIdx.x == 0) out[0] = s * (1.0f / NTOK);
}

// ---------------- probs = log_softmax(xf) over D, f32 out --------------------
__global__ __launch_bounds__(256) void probs_rows(const float* __restrict__ xf,
    float* __restrict__ out) {
  __shared__ float sh[4];
  int row = blockIdx.x, tid = threadIdx.x;
  const float* xr = xf + (size_t)row * DM;
  float4 v = *(const float4*)&xr[tid * 4];
  float m = block_max256(fmaxf(fmaxf(v.x, v.y), fmaxf(v.z, v.w)), sh);
  float ssum = __expf(v.x-m) + __expf(v.y-m) + __expf(v.z-m) + __expf(v.w-m);
  ssum = block_sum256(ssum, sh);
  float lg = m + logf(ssum);
  float* orow = out + (size_t)row * DM + tid * 4;   // 4B-aligned (odd base) -> scalar stores
  orow[0] = v.x - lg;
  orow[1] = v.y - lg;
  orow[2] = v.z - lg;
  orow[3] = v.w - lg;
}

// ============================================================================
extern "C" void kernel_launch(void* const* d_in, const int* in_sizes, int n_in,
                              void* d_out, int out_size, void* d_ws, size_t ws_size,
                              hipStream_t stream) {
  const int*   idx      = (const int*)  d_in[0];
  const int*   targets  = (const int*)  d_in[1];
  const float* word_emb = (const float*)d_in[2];
  const float* pos_emb  = (const float*)d_in[3];
  const float* ln1_g    = (const float*)d_in[4];
  const float* ln1_b    = (const float*)d_in[5];
  const float* wq       = (const float*)d_in[6];
  const float* wk       = (const float*)d_in[7];
  const float* wv       = (const float*)d_in[8];
  const float* proj_w   = (const float*)d_in[9];
  const float* proj_b   = (const float*)d_in[10];
  const float* ln2_g    = (const float*)d_in[11];
  const float* ln2_b    = (const float*)d_in[12];
  const float* ff_w1    = (const float*)d_in[13];
  const float* ff_b1    = (const float*)d_in[14];
  const float* ff_w2    = (const float*)d_in[15];
  const float* ff_b2    = (const float*)d_in[16];
  const float* lnf_g    = (const float*)d_in[17];
  const float* lnf_b    = (const float*)d_in[18];
  const float* lm_w     = (const float*)d_in[19];
  const float* lm_b     = (const float*)d_in[20];

  float* outf   = (float*)d_out;              // OUTPUT IS FLOAT32
  float* logits = outf + LOGITS_OFF;
  float* lossp  = outf + LOSS_OFF;
  float* maps   = outf + MAPS_OFF;
  float* probs  = outf + PROBS_OFF;

  const size_t ND = (size_t)NTOK * DM;        // 2,097,152
  const size_t NF = (size_t)NTOK * FFD;       // 8,388,608

  // Scratch in d_ws (~84 MB; R3-R5 confirmed ws_size >= this)
  float* x  = (float*)d_ws;
  float* h  = x  + ND;
  float* qb = h  + ND;
  float* kb = qb + ND;
  float* vb = kb + ND;
  float* ffh = vb + ND;
  float* xf  = ffh + NF;
  float* rowloss = xf + ND;

  dim3 b256(256);
  embed_kernel<<<dim3((NTOK * DM) / 256), b256, 0, stream>>>(idx, word_emb, pos_emb, x);

  for (int l = 0; l < LL; ++l) {
    const size_t wo = (size_t)l * DM * DM;
    ln_kernel<<<dim3(NTOK), b256, 0, stream>>>(x, ln1_g + l * DM, ln1_b + l * DM, h);
    gemm_k<0,0,0><<<dim3(DM/64, NTOK/64), b256, 0, stream>>>(h, wq + wo, nullptr, qb, NTOK, DM, DM);
    gemm_k<0,0,0><<<dim3(DM/64, NTOK/64), b256, 0, stream>>>(h, wk + wo, nullptr, kb, NTOK, DM, DM);
    gemm_k<0,0,0><<<dim3(DM/64, NTOK/64), b256, 0, stream>>>(h, wv + wo, nullptr, vb, NTOK, DM, DM);
    float* maps_l = maps + (size_t)l * BB * HH * TSEQ * TSEQ;
    attn_scores<<<dim3(TSEQ, BB*HH), b256, 0, stream>>>(qb, kb, maps_l);
    attn_av<<<dim3(TSEQ/4, BB*HH), b256, 0, stream>>>(maps_l, vb, h);   // h = att out
    gemm_k<1,1,0><<<dim3(DM/64, NTOK/64), b256, 0, stream>>>(h, proj_w + wo, proj_b + l * DM, x, NTOK, DM, DM);
    ln_kernel<<<dim3(NTOK), b256, 0, stream>>>(x, ln2_g + l * DM, ln2_b + l * DM, h);
    gemm_k<1,0,1><<<dim3(FFD/64, NTOK/64), b256, 0, stream>>>(h, ff_w1 + (size_t)l * DM * FFD, ff_b1 + l * FFD, ffh, NTOK, DM, FFD);
    gemm_k<1,1,0><<<dim3(DM/64, NTOK/64), b256, 0, stream>>>(ffh, ff_w2 + (size_t)l * FFD * DM, ff_b2 + l * DM, x, NTOK, FFD, DM);
  }

  ln_kernel<<<dim3(NTOK), b256, 0, stream>>>(x, lnf_g, lnf_b, xf);
  gemm_k<1,0,0><<<dim3(VSZ/64, NTOK/64), b256, 0, stream>>>(xf, lm_w, lm_b, logits, NTOK, DM, VSZ);
  loss_rows<<<dim3(NTOK), b256, 0, stream>>>(logits, targets, rowloss);
  loss_reduce<<<dim3(1), b256, 0, stream>>>(rowloss, lossp);
  probs_rows<<<dim3(NTOK), b256, 0, stream>>>(xf, probs);

  (void)in_sizes; (void)n_in; (void)out_size; (void)ws_size;
}

// Round 7
// 2467.691 us; speedup vs baseline: 2.4290x; 2.4290x over previous
//
#include <hip/hip_runtime.h>
#include <hip/hip_bf16.h>

// Decoder forward: B=2,T=1024,D=1024,H=16(hs=64),L=2,FF=4096,V=32000
// Outputs (FLOAT32, concat flat): logits[N,V], loss[1], maps[L,B,H,T,T], probs[N,D]
// Round 7: GEMMs -> bf16 MFMA (128x128 tile, reg-staged f32->bf16 into LDS);
// attn_av -> LDS-tiled f32 kernel. Everything else = validated R6 pipeline.
#define VSZ 32000
#define DM  1024
#define TSEQ 1024
#define BB  2
#define HH  16
#define LL  2
#define FFD 4096
#define NTOK (BB*TSEQ)   // 2048

static constexpr size_t LOGITS_OFF = 0;
static constexpr size_t LOSS_OFF   = (size_t)NTOK * VSZ;
static constexpr size_t MAPS_OFF   = LOSS_OFF + 1;
static constexpr size_t PROBS_OFF  = MAPS_OFF + (size_t)LL*BB*HH*TSEQ*TSEQ;

typedef __attribute__((ext_vector_type(8))) short bf8;
typedef __attribute__((ext_vector_type(4))) float f32x4;
typedef __attribute__((ext_vector_type(4))) short short4v;

__device__ __forceinline__ short f2bf(float f) {   // RTNE f32 -> bf16 bits
  union { float f; unsigned u; } v; v.f = f;
  unsigned r = v.u + 0x7FFFu + ((v.u >> 16) & 1u);
  return (short)(r >> 16);
}

// ---------------- reductions (block = 256 threads = 4 waves) ----------------
__device__ __forceinline__ float block_sum256(float v, float* sh) {
#pragma unroll
  for (int off = 32; off; off >>= 1) v += __shfl_down(v, off);
  int wid = threadIdx.x >> 6, lane = threadIdx.x & 63;
  if (lane == 0) sh[wid] = v;
  __syncthreads();
  v = sh[0] + sh[1] + sh[2] + sh[3];
  __syncthreads();
  return v;
}
__device__ __forceinline__ float block_max256(float v, float* sh) {
#pragma unroll
  for (int off = 32; off; off >>= 1) v = fmaxf(v, __shfl_down(v, off));
  int wid = threadIdx.x >> 6, lane = threadIdx.x & 63;
  if (lane == 0) sh[wid] = v;
  __syncthreads();
  v = fmaxf(fmaxf(sh[0], sh[1]), fmaxf(sh[2], sh[3]));
  __syncthreads();
  return v;
}

// ---------------- embedding ----------------
__global__ __launch_bounds__(256) void embed_kernel(const int* __restrict__ idx,
    const float* __restrict__ we, const float* __restrict__ pe, float* __restrict__ x) {
  int i = blockIdx.x * 256 + threadIdx.x;
  int n = i >> 10;
  int d = i & 1023;
  int t = n & (TSEQ - 1);
  x[i] = we[(size_t)idx[n] * DM + d] + pe[(size_t)t * DM + d];
}

// ---------------- LayerNorm over D=1024, one block per row ------------------
__global__ __launch_bounds__(256) void ln_kernel(const float* __restrict__ in,
    const float* __restrict__ g, const float* __restrict__ b, float* __restrict__ out) {
  __shared__ float sh[4];
  int row = blockIdx.x, tid = threadIdx.x;
  const float* xr = in + (size_t)row * DM;
  float4 v = *(const float4*)&xr[tid * 4];
  float s  = v.x + v.y + v.z + v.w;
  float s2 = v.x*v.x + v.y*v.y + v.z*v.z + v.w*v.w;
  s  = block_sum256(s, sh);
  s2 = block_sum256(s2, sh);
  float mean = s * (1.0f / DM);
  float var  = s2 * (1.0f / DM) - mean * mean;
  float inv  = rsqrtf(var + 1e-5f);
  float4 gv = *(const float4*)&g[tid * 4];
  float4 bv = *(const float4*)&b[tid * 4];
  float4 o;
  o.x = (v.x - mean) * inv * gv.x + bv.x;
  o.y = (v.y - mean) * inv * gv.y + bv.y;
  o.z = (v.z - mean) * inv * gv.z + bv.z;
  o.w = (v.w - mean) * inv * gv.w + bv.w;
  *(float4*)&out[(size_t)row * DM + tid * 4] = o;
}

// ---------------- bf16-MFMA GEMM: C[M,N] = A[M,K] @ B[K,N] (f32 in/out) -----
// 128x128 tile, BK=32, 4 waves (2x2), each wave 64x64 = 4x4 frags of 16x16x32.
// A,B staged f32->bf16 (RTNE) into LDS, rows padded to 40 shorts (80B).
template<int BIAS, int RES, int RELU>
__global__ __launch_bounds__(256) void gemm_mfma(const float* __restrict__ A,
    const float* __restrict__ Bw, const float* __restrict__ bias,
    float* __restrict__ C, int M, int K, int Nn) {
  __shared__ short As[128 * 40];
  __shared__ short Bs[128 * 40];
  const int tid  = threadIdx.x;
  const int bm   = blockIdx.y * 128, bn = blockIdx.x * 128;
  const int lane = tid & 63, wid = tid >> 6;
  const int wr = wid >> 1, wc = wid & 1;      // wave 2x2 grid
  const int lr = lane & 15, lg = lane >> 4;   // frag row/col & k-group
  // A staging map: 4 passes, row = tid>>3 (+32/pass), kq = (tid&7)*4
  const int sar = tid >> 3, sak = (tid & 7) * 4;
  // B staging map: n = tid&127, khalf = tid>>7 (16 k each)
  const int sbn = tid & 127, sbk = (tid >> 7) * 16;

  f32x4 acc[4][4];
#pragma unroll
  for (int i = 0; i < 4; ++i)
#pragma unroll
    for (int j = 0; j < 4; ++j) acc[i][j] = (f32x4)0.f;

  for (int k0 = 0; k0 < K; k0 += 32) {
    // ---- stage A (128x32) ----
#pragma unroll
    for (int p = 0; p < 4; ++p) {
      int row = sar + p * 32;
      float4 a4 = *(const float4*)&A[(size_t)(bm + row) * K + k0 + sak];
      short4v s4;
      s4.x = f2bf(a4.x); s4.y = f2bf(a4.y); s4.z = f2bf(a4.z); s4.w = f2bf(a4.w);
      *(short4v*)&As[row * 40 + sak] = s4;
    }
    // ---- stage B (32x128) transposed -> Bs[n][k] ----
    {
      short tmp[16];
#pragma unroll
      for (int e = 0; e < 16; ++e)
        tmp[e] = f2bf(Bw[(size_t)(k0 + sbk + e) * Nn + bn + sbn]);
      *(bf8*)&Bs[sbn * 40 + sbk    ] = *(bf8*)&tmp[0];
      *(bf8*)&Bs[sbn * 40 + sbk + 8] = *(bf8*)&tmp[8];
    }
    __syncthreads();
    // ---- compute ----
    bf8 af[4], bf[4];
#pragma unroll
    for (int i = 0; i < 4; ++i)
      af[i] = *(const bf8*)&As[(wr * 64 + i * 16 + lr) * 40 + lg * 8];
#pragma unroll
    for (int j = 0; j < 4; ++j)
      bf[j] = *(const bf8*)&Bs[(wc * 64 + j * 16 + lr) * 40 + lg * 8];
#pragma unroll
    for (int i = 0; i < 4; ++i)
#pragma unroll
      for (int j = 0; j < 4; ++j)
        acc[i][j] = __builtin_amdgcn_mfma_f32_16x16x32_bf16(af[i], bf[j], acc[i][j], 0, 0, 0);
    __syncthreads();
  }
  // ---- epilogue: C/D map col=lane&15, row=(lane>>4)*4+v ----
#pragma unroll
  for (int i = 0; i < 4; ++i) {
#pragma unroll
    for (int v = 0; v < 4; ++v) {
      int row = bm + wr * 64 + i * 16 + lg * 4 + v;
      size_t rowb = (size_t)row * Nn;
#pragma unroll
      for (int j = 0; j < 4; ++j) {
        int col = bn + wc * 64 + j * 16 + lr;
        float val = acc[i][j][v];
        if (BIAS) val += bias[col];
        if (RES)  val += C[rowb + col];
        if (RELU) val = fmaxf(val, 0.f);
        C[rowb + col] = val;
      }
    }
  }
}

// ---------------- attention scores + causal softmax -> maps (f32) -----------
__global__ __launch_bounds__(256) void attn_scores(const float* __restrict__ qb,
    const float* __restrict__ kb, float* __restrict__ maps_l) {
  __shared__ float qv[64];
  __shared__ float sh[4];
  const int q = blockIdx.x;
  const int bh = blockIdx.y;
  const int b = bh >> 4, h = bh & 15;
  const int tid = threadIdx.x;
  if (tid < 64) qv[tid] = qb[(size_t)(b * TSEQ + q) * DM + h * 64 + tid];
  __syncthreads();
  const float scale = 0.03125f;
  float s[4];
#pragma unroll
  for (int i = 0; i < 4; ++i) {
    int kp = tid + i * 256;
    if (kp <= q) {
      const float4* kv = (const float4*)&kb[(size_t)(b * TSEQ + kp) * DM + h * 64];
      float acc = 0.f;
#pragma unroll
      for (int d = 0; d < 16; ++d) {
        float4 k4 = kv[d];
        acc += qv[d*4]*k4.x + qv[d*4+1]*k4.y + qv[d*4+2]*k4.z + qv[d*4+3]*k4.w;
      }
      s[i] = acc * scale;
    } else s[i] = -1e30f;
  }
  float m = block_max256(fmaxf(fmaxf(s[0], s[1]), fmaxf(s[2], s[3])), sh);
  float e[4]; float ssum = 0.f;
#pragma unroll
  for (int i = 0; i < 4; ++i) {
    int kp = tid + i * 256;
    e[i] = (kp <= q) ? __expf(s[i] - m) : 0.f;
    ssum += e[i];
  }
  ssum = block_sum256(ssum, sh);
  float inv = 1.f / ssum;
  float* mrow = maps_l + (size_t)bh * TSEQ * TSEQ + (size_t)q * TSEQ;
#pragma unroll
  for (int i = 0; i < 4; ++i) mrow[tid + i * 256] = e[i] * inv;
}

// ---------------- att = wei @ v, LDS-tiled ----------------------------------
// grid (T/32, B*H); block 256 = 32 q-rows x 8 d-groups (8 d each).
// Relies on maps having exact zeros beyond the causal boundary.
__global__ __launch_bounds__(256) void attn_av2(const float* __restrict__ maps_l,
    const float* __restrict__ vb, float* __restrict__ outp) {
  __shared__ float Vs[64][68];
  __shared__ float Ws[32][66];
  const int tid = threadIdx.x;
  const int ql = tid >> 3, dg = tid & 7;
  const int q0 = blockIdx.x * 32;
  const int bh = blockIdx.y;
  const int b = bh >> 4, h = bh & 15;
  const float* wbase = maps_l + (size_t)bh * TSEQ * TSEQ;
  const int vr = tid >> 2, vc = (tid & 3) * 16;      // V staging map
  const int wrow = tid >> 3, wc8 = (tid & 7) * 8;    // W staging map
  float4 a0 = {0,0,0,0}, a1 = {0,0,0,0};
  const int ntiles = (q0 + 32 + 63) >> 6;
  for (int kt = 0; kt < ntiles; ++kt) {
    const int kb0 = kt * 64;
#pragma unroll
    for (int e = 0; e < 4; ++e)
      *(float4*)&Vs[vr][vc + e * 4] =
        *(const float4*)&vb[(size_t)(b * TSEQ + kb0 + vr) * DM + h * 64 + vc + e * 4];
#pragma unroll
    for (int e = 0; e < 4; ++e)
      *(float2*)&Ws[wrow][wc8 + e * 2] =
        *(const float2*)&wbase[(size_t)(q0 + wrow) * TSEQ + kb0 + wc8 + e * 2];
    __syncthreads();
#pragma unroll 8
    for (int k = 0; k < 64; ++k) {
      float w = Ws[ql][k];
      float4 v0 = *(const float4*)&Vs[k][dg * 8];
      float4 v1 = *(const float4*)&Vs[k][dg * 8 + 4];
      a0.x += w * v0.x; a0.y += w * v0.y; a0.z += w * v0.z; a0.w += w * v0.w;
      a1.x += w * v1.x; a1.y += w * v1.y; a1.z += w * v1.z; a1.w += w * v1.w;
    }
    __syncthreads();
  }
  float* orow = &outp[(size_t)(b * TSEQ + q0 + ql) * DM + h * 64 + dg * 8];
  *(float4*)&orow[0] = a0;
  *(float4*)&orow[4] = a1;
}

// ---------------- per-row CE loss from f32 logits ----------------------------
__global__ __launch_bounds__(256) void loss_rows(const float* __restrict__ logits,
    const int* __restrict__ targets, float* __restrict__ rowloss) {
  __shared__ float sh[4];
  int row = blockIdx.x, tid = threadIdx.x;
  const float* lr = logits + (size_t)row * VSZ;
  float m = -1e30f;
  for (int i = tid; i < VSZ; i += 256) m = fmaxf(m, lr[i]);
  m = block_max256(m, sh);
  float ssum = 0.f;
  for (int i = tid; i < VSZ; i += 256) ssum += __expf(lr[i] - m);
  ssum = block_sum256(ssum, sh);
  if (tid == 0)
    rowloss[row] = m + logf(ssum) - lr[targets[row]];
}
__global__ __launch_bounds__(256) void loss_reduce(const float* __restrict__ rowloss,
    float* __restrict__ out) {
  __shared__ float sh[4];
  float s = 0.f;
  for (int i = threadIdx.x; i < NTOK; i += 256) s += rowloss[i];
  s = block_sum256(s, sh);
  if (threadIdx.x == 0) out[0] = s * (1.0f / NTOK);
}

// ---------------- probs = log_softmax(xf) over D, f32 out --------------------
__global__ __launch_bounds__(256) void probs_rows(const float* __restrict__ xf,
    float* __restrict__ out) {
  __shared__ float sh[4];
  int row = blockIdx.x, tid = threadIdx.x;
  const float* xr = xf + (size_t)row * DM;
  float4 v = *(const float4*)&xr[tid * 4];
  float m = block_max256(fmaxf(fmaxf(v.x, v.y), fmaxf(v.z, v.w)), sh);
  float ssum = __expf(v.x-m) + __expf(v.y-m) + __expf(v.z-m) + __expf(v.w-m);
  ssum = block_sum256(ssum, sh);
  float lg = m + logf(ssum);
  float* orow = out + (size_t)row * DM + tid * 4;
  orow[0] = v.x - lg;
  orow[1] = v.y - lg;
  orow[2] = v.z - lg;
  orow[3] = v.w - lg;
}

// ============================================================================
extern "C" void kernel_launch(void* const* d_in, const int* in_sizes, int n_in,
                              void* d_out, int out_size, void* d_ws, size_t ws_size,
                              hipStream_t stream) {
  const int*   idx      = (const int*)  d_in[0];
  const int*   targets  = (const int*)  d_in[1];
  const float* word_emb = (const float*)d_in[2];
  const float* pos_emb  = (const float*)d_in[3];
  const float* ln1_g    = (const float*)d_in[4];
  const float* ln1_b    = (const float*)d_in[5];
  const float* wq       = (const float*)d_in[6];
  const float* wk       = (const float*)d_in[7];
  const float* wv       = (const float*)d_in[8];
  const float* proj_w   = (const float*)d_in[9];
  const float* proj_b   = (const float*)d_in[10];
  const float* ln2_g    = (const float*)d_in[11];
  const float* ln2_b    = (const float*)d_in[12];
  const float* ff_w1    = (const float*)d_in[13];
  const float* ff_b1    = (const float*)d_in[14];
  const float* ff_w2    = (const float*)d_in[15];
  const float* ff_b2    = (const float*)d_in[16];
  const float* lnf_g    = (const float*)d_in[17];
  const float* lnf_b    = (const float*)d_in[18];
  const float* lm_w     = (const float*)d_in[19];
  const float* lm_b     = (const float*)d_in[20];

  float* outf   = (float*)d_out;              // output is f32
  float* logits = outf + LOGITS_OFF;
  float* lossp  = outf + LOSS_OFF;
  float* maps   = outf + MAPS_OFF;
  float* probs  = outf + PROBS_OFF;

  const size_t ND = (size_t)NTOK * DM;
  const size_t NF = (size_t)NTOK * FFD;

  float* x  = (float*)d_ws;
  float* h  = x  + ND;
  float* qb = h  + ND;
  float* kb = qb + ND;
  float* vb = kb + ND;
  float* ffh = vb + ND;
  float* xf  = ffh + NF;
  float* rowloss = xf + ND;

  dim3 b256(256);
  embed_kernel<<<dim3((NTOK * DM) / 256), b256, 0, stream>>>(idx, word_emb, pos_emb, x);

  for (int l = 0; l < LL; ++l) {
    const size_t wo = (size_t)l * DM * DM;
    ln_kernel<<<dim3(NTOK), b256, 0, stream>>>(x, ln1_g + l * DM, ln1_b + l * DM, h);
    gemm_mfma<0,0,0><<<dim3(DM/128, NTOK/128), b256, 0, stream>>>(h, wq + wo, nullptr, qb, NTOK, DM, DM);
    gemm_mfma<0,0,0><<<dim3(DM/128, NTOK/128), b256, 0, stream>>>(h, wk + wo, nullptr, kb, NTOK, DM, DM);
    gemm_mfma<0,0,0><<<dim3(DM/128, NTOK/128), b256, 0, stream>>>(h, wv + wo, nullptr, vb, NTOK, DM, DM);
    float* maps_l = maps + (size_t)l * BB * HH * TSEQ * TSEQ;
    attn_scores<<<dim3(TSEQ, BB*HH), b256, 0, stream>>>(qb, kb, maps_l);
    attn_av2<<<dim3(TSEQ/32, BB*HH), b256, 0, stream>>>(maps_l, vb, h);   // h = att out
    gemm_mfma<1,1,0><<<dim3(DM/128, NTOK/128), b256, 0, stream>>>(h, proj_w + wo, proj_b + l * DM, x, NTOK, DM, DM);
    ln_kernel<<<dim3(NTOK), b256, 0, stream>>>(x, ln2_g + l * DM, ln2_b + l * DM, h);
    gemm_mfma<1,0,1><<<dim3(FFD/128, NTOK/128), b256, 0, stream>>>(h, ff_w1 + (size_t)l * DM * FFD, ff_b1 + l * FFD, ffh, NTOK, DM, FFD);
    gemm_mfma<1,1,0><<<dim3(DM/128, NTOK/128), b256, 0, stream>>>(ffh, ff_w2 + (size_t)l * FFD * DM, ff_b2 + l * DM, x, NTOK, FFD, DM);
  }

  ln_kernel<<<dim3(NTOK), b256, 0, stream>>>(x, lnf_g, lnf_b, xf);
  gemm_mfma<1,0,0><<<dim3(VSZ/128, NTOK/128), b256, 0, stream>>>(xf, lm_w, lm_b, logits, NTOK, DM, VSZ);
  loss_rows<<<dim3(NTOK), b256, 0, stream>>>(logits, targets, rowloss);
  loss_reduce<<<dim3(1), b256, 0, stream>>>(rowloss, lossp);
  probs_rows<<<dim3(NTOK), b256, 0, stream>>>(xf, probs);

  (void)in_sizes; (void)n_in; (void)out_size; (void)ws_size;
}

// Round 8
// 1660.022 us; speedup vs baseline: 3.6108x; 1.4865x over previous
//
#include <hip/hip_runtime.h>
#include <hip/hip_bf16.h>

// Decoder forward: B=2,T=1024,D=1024,H=16(hs=64),L=2,FF=4096,V=32000
// Outputs (FLOAT32, concat flat): logits[N,V], loss[1], maps[L,B,H,T,T], probs[N,D]
// Round 8: attn_scores -> MFMA QK^T (raw scores to maps) + in-place row softmax.
#define VSZ 32000
#define DM  1024
#define TSEQ 1024
#define BB  2
#define HH  16
#define LL  2
#define FFD 4096
#define NTOK (BB*TSEQ)   // 2048

static constexpr size_t LOGITS_OFF = 0;
static constexpr size_t LOSS_OFF   = (size_t)NTOK * VSZ;
static constexpr size_t MAPS_OFF   = LOSS_OFF + 1;
static constexpr size_t PROBS_OFF  = MAPS_OFF + (size_t)LL*BB*HH*TSEQ*TSEQ;

typedef __attribute__((ext_vector_type(8))) short bf8;
typedef __attribute__((ext_vector_type(4))) float f32x4;
typedef __attribute__((ext_vector_type(4))) short short4v;

__device__ __forceinline__ short f2bf(float f) {   // RTNE f32 -> bf16 bits
  union { float f; unsigned u; } v; v.f = f;
  unsigned r = v.u + 0x7FFFu + ((v.u >> 16) & 1u);
  return (short)(r >> 16);
}

// ---------------- reductions (block = 256 threads = 4 waves) ----------------
__device__ __forceinline__ float block_sum256(float v, float* sh) {
#pragma unroll
  for (int off = 32; off; off >>= 1) v += __shfl_down(v, off);
  int wid = threadIdx.x >> 6, lane = threadIdx.x & 63;
  if (lane == 0) sh[wid] = v;
  __syncthreads();
  v = sh[0] + sh[1] + sh[2] + sh[3];
  __syncthreads();
  return v;
}
__device__ __forceinline__ float block_max256(float v, float* sh) {
#pragma unroll
  for (int off = 32; off; off >>= 1) v = fmaxf(v, __shfl_down(v, off));
  int wid = threadIdx.x >> 6, lane = threadIdx.x & 63;
  if (lane == 0) sh[wid] = v;
  __syncthreads();
  v = fmaxf(fmaxf(sh[0], sh[1]), fmaxf(sh[2], sh[3]));
  __syncthreads();
  return v;
}

// ---------------- embedding ----------------
__global__ __launch_bounds__(256) void embed_kernel(const int* __restrict__ idx,
    const float* __restrict__ we, const float* __restrict__ pe, float* __restrict__ x) {
  int i = blockIdx.x * 256 + threadIdx.x;
  int n = i >> 10;
  int d = i & 1023;
  int t = n & (TSEQ - 1);
  x[i] = we[(size_t)idx[n] * DM + d] + pe[(size_t)t * DM + d];
}

// ---------------- LayerNorm over D=1024, one block per row ------------------
__global__ __launch_bounds__(256) void ln_kernel(const float* __restrict__ in,
    const float* __restrict__ g, const float* __restrict__ b, float* __restrict__ out) {
  __shared__ float sh[4];
  int row = blockIdx.x, tid = threadIdx.x;
  const float* xr = in + (size_t)row * DM;
  float4 v = *(const float4*)&xr[tid * 4];
  float s  = v.x + v.y + v.z + v.w;
  float s2 = v.x*v.x + v.y*v.y + v.z*v.z + v.w*v.w;
  s  = block_sum256(s, sh);
  s2 = block_sum256(s2, sh);
  float mean = s * (1.0f / DM);
  float var  = s2 * (1.0f / DM) - mean * mean;
  float inv  = rsqrtf(var + 1e-5f);
  float4 gv = *(const float4*)&g[tid * 4];
  float4 bv = *(const float4*)&b[tid * 4];
  float4 o;
  o.x = (v.x - mean) * inv * gv.x + bv.x;
  o.y = (v.y - mean) * inv * gv.y + bv.y;
  o.z = (v.z - mean) * inv * gv.z + bv.z;
  o.w = (v.w - mean) * inv * gv.w + bv.w;
  *(float4*)&out[(size_t)row * DM + tid * 4] = o;
}

// ---------------- bf16-MFMA GEMM (verified in R7) ---------------------------
template<int BIAS, int RES, int RELU>
__global__ __launch_bounds__(256) void gemm_mfma(const float* __restrict__ A,
    const float* __restrict__ Bw, const float* __restrict__ bias,
    float* __restrict__ C, int M, int K, int Nn) {
  __shared__ short As[128 * 40];
  __shared__ short Bs[128 * 40];
  const int tid  = threadIdx.x;
  const int bm   = blockIdx.y * 128, bn = blockIdx.x * 128;
  const int lane = tid & 63, wid = tid >> 6;
  const int wr = wid >> 1, wc = wid & 1;
  const int lr = lane & 15, lg = lane >> 4;
  const int sar = tid >> 3, sak = (tid & 7) * 4;
  const int sbn = tid & 127, sbk = (tid >> 7) * 16;

  f32x4 acc[4][4];
#pragma unroll
  for (int i = 0; i < 4; ++i)
#pragma unroll
    for (int j = 0; j < 4; ++j) acc[i][j] = (f32x4)0.f;

  for (int k0 = 0; k0 < K; k0 += 32) {
#pragma unroll
    for (int p = 0; p < 4; ++p) {
      int row = sar + p * 32;
      float4 a4 = *(const float4*)&A[(size_t)(bm + row) * K + k0 + sak];
      short4v s4;
      s4.x = f2bf(a4.x); s4.y = f2bf(a4.y); s4.z = f2bf(a4.z); s4.w = f2bf(a4.w);
      *(short4v*)&As[row * 40 + sak] = s4;
    }
    {
      short tmp[16];
#pragma unroll
      for (int e = 0; e < 16; ++e)
        tmp[e] = f2bf(Bw[(size_t)(k0 + sbk + e) * Nn + bn + sbn]);
      *(bf8*)&Bs[sbn * 40 + sbk    ] = *(bf8*)&tmp[0];
      *(bf8*)&Bs[sbn * 40 + sbk + 8] = *(bf8*)&tmp[8];
    }
    __syncthreads();
    bf8 af[4], bfv[4];
#pragma unroll
    for (int i = 0; i < 4; ++i)
      af[i] = *(const bf8*)&As[(wr * 64 + i * 16 + lr) * 40 + lg * 8];
#pragma unroll
    for (int j = 0; j < 4; ++j)
      bfv[j] = *(const bf8*)&Bs[(wc * 64 + j * 16 + lr) * 40 + lg * 8];
#pragma unroll
    for (int i = 0; i < 4; ++i)
#pragma unroll
      for (int j = 0; j < 4; ++j)
        acc[i][j] = __builtin_amdgcn_mfma_f32_16x16x32_bf16(af[i], bfv[j], acc[i][j], 0, 0, 0);
    __syncthreads();
  }
#pragma unroll
  for (int i = 0; i < 4; ++i) {
#pragma unroll
    for (int v = 0; v < 4; ++v) {
      int row = bm + wr * 64 + i * 16 + lg * 4 + v;
      size_t rowb = (size_t)row * Nn;
#pragma unroll
      for (int j = 0; j < 4; ++j) {
        int col = bn + wc * 64 + j * 16 + lr;
        float val = acc[i][j][v];
        if (BIAS) val += bias[col];
        if (RES)  val += C[rowb + col];
        if (RELU) val = fmaxf(val, 0.f);
        C[rowb + col] = val;
      }
    }
  }
}

// ---------------- MFMA QK^T: raw scaled scores -> maps (triangular) ---------
// grid (T/64, B*H); block 256 = 4 waves (2x2), each wave 32x32 per k-tile.
__global__ __launch_bounds__(256) void attn_qkt(const float* __restrict__ qb,
    const float* __restrict__ kb, float* __restrict__ maps_l) {
  __shared__ short Qs[64 * 72];
  __shared__ short Ks[64 * 72];
  const int tid = threadIdx.x;
  const int qi = blockIdx.x;
  const int bh = blockIdx.y;
  const int b = bh >> 4, h = bh & 15;
  const int q0 = qi * 64;
  const int lane = tid & 63, wid = tid >> 6;
  const int wr = wid >> 1, wc = wid & 1;
  const int lr = lane & 15, lg = lane >> 4;
  const int sr = tid >> 2, sc = (tid & 3) * 16;
  {
    const float* src = &qb[(size_t)(b * TSEQ + q0 + sr) * DM + h * 64 + sc];
    short tmp[16];
#pragma unroll
    for (int e = 0; e < 16; ++e) tmp[e] = f2bf(src[e]);
    *(bf8*)&Qs[sr * 72 + sc    ] = *(bf8*)&tmp[0];
    *(bf8*)&Qs[sr * 72 + sc + 8] = *(bf8*)&tmp[8];
  }
  float* mbase = maps_l + (size_t)bh * TSEQ * TSEQ;
  for (int kt = 0; kt <= qi; ++kt) {
    const int k0 = kt * 64;
    {
      const float* src = &kb[(size_t)(b * TSEQ + k0 + sr) * DM + h * 64 + sc];
      short tmp[16];
#pragma unroll
      for (int e = 0; e < 16; ++e) tmp[e] = f2bf(src[e]);
      *(bf8*)&Ks[sr * 72 + sc    ] = *(bf8*)&tmp[0];
      *(bf8*)&Ks[sr * 72 + sc + 8] = *(bf8*)&tmp[8];
    }
    __syncthreads();
    f32x4 acc[2][2];
#pragma unroll
    for (int i = 0; i < 2; ++i)
#pragma unroll
      for (int j = 0; j < 2; ++j) acc[i][j] = (f32x4)0.f;
#pragma unroll
    for (int ds = 0; ds < 2; ++ds) {
      bf8 af[2], bfv[2];
#pragma unroll
      for (int i = 0; i < 2; ++i)
        af[i] = *(const bf8*)&Qs[(wr * 32 + i * 16 + lr) * 72 + ds * 32 + lg * 8];
#pragma unroll
      for (int j = 0; j < 2; ++j)
        bfv[j] = *(const bf8*)&Ks[(wc * 32 + j * 16 + lr) * 72 + ds * 32 + lg * 8];
#pragma unroll
      for (int i = 0; i < 2; ++i)
#pragma unroll
        for (int j = 0; j < 2; ++j)
          acc[i][j] = __builtin_amdgcn_mfma_f32_16x16x32_bf16(af[i], bfv[j], acc[i][j], 0, 0, 0);
    }
#pragma unroll
    for (int i = 0; i < 2; ++i)
#pragma unroll
      for (int v = 0; v < 4; ++v) {
        int row = q0 + wr * 32 + i * 16 + lg * 4 + v;
#pragma unroll
        for (int j = 0; j < 2; ++j) {
          int col = k0 + wc * 32 + j * 16 + lr;
          mbase[(size_t)row * TSEQ + col] = acc[i][j][v] * 0.03125f;
        }
      }
    __syncthreads();
  }
}

// ---------------- in-place causal row softmax over maps ---------------------
__global__ __launch_bounds__(256) void attn_softmax(float* __restrict__ maps_l) {
  __shared__ float sh[4];
  const int q = blockIdx.x, bh = blockIdx.y;
  const int tid = threadIdx.x;
  float* mrow = maps_l + (size_t)bh * TSEQ * TSEQ + (size_t)q * TSEQ;
  float s[4];
#pragma unroll
  for (int i = 0; i < 4; ++i) {
    int kp = tid + i * 256;
    s[i] = (kp <= q) ? mrow[kp] : -1e30f;
  }
  float m = block_max256(fmaxf(fmaxf(s[0], s[1]), fmaxf(s[2], s[3])), sh);
  float e[4]; float ssum = 0.f;
#pragma unroll
  for (int i = 0; i < 4; ++i) {
    int kp = tid + i * 256;
    e[i] = (kp <= q) ? __expf(s[i] - m) : 0.f;
    ssum += e[i];
  }
  ssum = block_sum256(ssum, sh);
  float inv = 1.f / ssum;
#pragma unroll
  for (int i = 0; i < 4; ++i) mrow[tid + i * 256] = e[i] * inv;
}

// ---------------- att = wei @ v, LDS-tiled (R7, verified) -------------------
__global__ __launch_bounds__(256) void attn_av2(const float* __restrict__ maps_l,
    const float* __restrict__ vb, float* __restrict__ outp) {
  __shared__ float Vs[64][68];
  __shared__ float Ws[32][66];
  const int tid = threadIdx.x;
  const int ql = tid >> 3, dg = tid & 7;
  const int q0 = blockIdx.x * 32;
  const int bh = blockIdx.y;
  const int b = bh >> 4, h = bh & 15;
  const float* wbase = maps_l + (size_t)bh * TSEQ * TSEQ;
  const int vr = tid >> 2, vc = (tid & 3) * 16;
  const int wrow = tid >> 3, wc8 = (tid & 7) * 8;
  float4 a0 = {0,0,0,0}, a1 = {0,0,0,0};
  const int ntiles = (q0 + 32 + 63) >> 6;
  for (int kt = 0; kt < ntiles; ++kt) {
    const int kb0 = kt * 64;
#pragma unroll
    for (int e = 0; e < 4; ++e)
      *(float4*)&Vs[vr][vc + e * 4] =
        *(const float4*)&vb[(size_t)(b * TSEQ + kb0 + vr) * DM + h * 64 + vc + e * 4];
#pragma unroll
    for (int e = 0; e < 4; ++e)
      *(float2*)&Ws[wrow][wc8 + e * 2] =
        *(const float2*)&wbase[(size_t)(q0 + wrow) * TSEQ + kb0 + wc8 + e * 2];
    __syncthreads();
#pragma unroll 8
    for (int k = 0; k < 64; ++k) {
      float w = Ws[ql][k];
      float4 v0 = *(const float4*)&Vs[k][dg * 8];
      float4 v1 = *(const float4*)&Vs[k][dg * 8 + 4];
      a0.x += w * v0.x; a0.y += w * v0.y; a0.z += w * v0.z; a0.w += w * v0.w;
      a1.x += w * v1.x; a1.y += w * v1.y; a1.z += w * v1.z; a1.w += w * v1.w;
    }
    __syncthreads();
  }
  float* orow = &outp[(size_t)(b * TSEQ + q0 + ql) * DM + h * 64 + dg * 8];
  *(float4*)&orow[0] = a0;
  *(float4*)&orow[4] = a1;
}

// ---------------- per-row CE loss from f32 logits ----------------------------
__global__ __launch_bounds__(256) void loss_rows(const float* __restrict__ logits,
    const int* __restrict__ targets, float* __restrict__ rowloss) {
  __shared__ float sh[4];
  int row = blockIdx.x, tid = threadIdx.x;
  const float* lr = logits + (size_t)row * VSZ;
  float m = -1e30f;
  for (int i = tid; i < VSZ; i += 256) m = fmaxf(m, lr[i]);
  m = block_max256(m, sh);
  float ssum = 0.f;
  for (int i = tid; i < VSZ; i += 256) ssum += __expf(lr[i] - m);
  ssum = block_sum256(ssum, sh);
  if (tid == 0)
    rowloss[row] = m + logf(ssum) - lr[targets[row]];
}
__global__ __launch_bounds__(256) void loss_reduce(const float* __restrict__ rowloss,
    float* __restrict__ out) {
  __shared__ float sh[4];
  float s = 0.f;
  for (int i = threadIdx.x; i < NTOK; i += 256) s += rowloss[i];
  s = block_sum256(s, sh);
  if (threadIdx.x == 0) out[0] = s * (1.0f / NTOK);
}

// ---------------- probs = log_softmax(xf) over D, f32 out --------------------
__global__ __launch_bounds__(256) void probs_rows(const float* __restrict__ xf,
    float* __restrict__ out) {
  __shared__ float sh[4];
  int row = blockIdx.x, tid = threadIdx.x;
  const float* xr = xf + (size_t)row * DM;
  float4 v = *(const float4*)&xr[tid * 4];
  float m = block_max256(fmaxf(fmaxf(v.x, v.y), fmaxf(v.z, v.w)), sh);
  float ssum = __expf(v.x-m) + __expf(v.y-m) + __expf(v.z-m) + __expf(v.w-m);
  ssum = block_sum256(ssum, sh);
  float lg = m + logf(ssum);
  float* orow = out + (size_t)row * DM + tid * 4;
  orow[0] = v.x - lg;
  orow[1] = v.y - lg;
  orow[2] = v.z - lg;
  orow[3] = v.w - lg;
}

// ============================================================================
extern "C" void kernel_launch(void* const* d_in, const int* in_sizes, int n_in,
                              void* d_out, int out_size, void* d_ws, size_t ws_size,
                              hipStream_t stream) {
  const int*   idx      = (const int*)  d_in[0];
  const int*   targets  = (const int*)  d_in[1];
  const float* word_emb = (const float*)d_in[2];
  const float* pos_emb  = (const float*)d_in[3];
  const float* ln1_g    = (const float*)d_in[4];
  const float* ln1_b    = (const float*)d_in[5];
  const float* wq       = (const float*)d_in[6];
  const float* wk       = (const float*)d_in[7];
  const float* wv       = (const float*)d_in[8];
  const float* proj_w   = (const float*)d_in[9];
  const float* proj_b   = (const float*)d_in[10];
  const float* ln2_g    = (const float*)d_in[11];
  const float* ln2_b    = (const float*)d_in[12];
  const float* ff_w1    = (const float*)d_in[13];
  const float* ff_b1    = (const float*)d_in[14];
  const float* ff_w2    = (const float*)d_in[15];
  const float* ff_b2    = (const float*)d_in[16];
  const float* lnf_g    = (const float*)d_in[17];
  const float* lnf_b    = (const float*)d_in[18];
  const float* lm_w     = (const float*)d_in[19];
  const float* lm_b     = (const float*)d_in[20];

  float* outf   = (float*)d_out;
  float* logits = outf + LOGITS_OFF;
  float* lossp  = outf + LOSS_OFF;
  float* maps   = outf + MAPS_OFF;
  float* probs  = outf + PROBS_OFF;

  const size_t ND = (size_t)NTOK * DM;
  const size_t NF = (size_t)NTOK * FFD;

  float* x  = (float*)d_ws;
  float* h  = x  + ND;
  float* qb = h  + ND;
  float* kb = qb + ND;
  float* vb = kb + ND;
  float* ffh = vb + ND;
  float* xf  = ffh + NF;
  float* rowloss = xf + ND;

  dim3 b256(256);
  embed_kernel<<<dim3((NTOK * DM) / 256), b256, 0, stream>>>(idx, word_emb, pos_emb, x);

  for (int l = 0; l < LL; ++l) {
    const size_t wo = (size_t)l * DM * DM;
    ln_kernel<<<dim3(NTOK), b256, 0, stream>>>(x, ln1_g + l * DM, ln1_b + l * DM, h);
    gemm_mfma<0,0,0><<<dim3(DM/128, NTOK/128), b256, 0, stream>>>(h, wq + wo, nullptr, qb, NTOK, DM, DM);
    gemm_mfma<0,0,0><<<dim3(DM/128, NTOK/128), b256, 0, stream>>>(h, wk + wo, nullptr, kb, NTOK, DM, DM);
    gemm_mfma<0,0,0><<<dim3(DM/128, NTOK/128), b256, 0, stream>>>(h, wv + wo, nullptr, vb, NTOK, DM, DM);
    float* maps_l = maps + (size_t)l * BB * HH * TSEQ * TSEQ;
    attn_qkt<<<dim3(TSEQ/64, BB*HH), b256, 0, stream>>>(qb, kb, maps_l);
    attn_softmax<<<dim3(TSEQ, BB*HH), b256, 0, stream>>>(maps_l);
    attn_av2<<<dim3(TSEQ/32, BB*HH), b256, 0, stream>>>(maps_l, vb, h);
    gemm_mfma<1,1,0><<<dim3(DM/128, NTOK/128), b256, 0, stream>>>(h, proj_w + wo, proj_b + l * DM, x, NTOK, DM, DM);
    ln_kernel<<<dim3(NTOK), b256, 0, stream>>>(x, ln2_g + l * DM, ln2_b + l * DM, h);
    gemm_mfma<1,0,1><<<dim3(FFD/128, NTOK/128), b256, 0, stream>>>(h, ff_w1 + (size_t)l * DM * FFD, ff_b1 + l * FFD, ffh, NTOK, DM, FFD);
    gemm_mfma<1,1,0><<<dim3(DM/128, NTOK/128), b256, 0, stream>>>(ffh, ff_w2 + (size_t)l * FFD * DM, ff_b2 + l * DM, x, NTOK, FFD, DM);
  }

  ln_kernel<<<dim3(NTOK), b256, 0, stream>>>(x, lnf_g, lnf_b, xf);
  gemm_mfma<1,0,0><<<dim3(VSZ/128, NTOK/128), b256, 0, stream>>>(xf, lm_w, lm_b, logits, NTOK, DM, VSZ);
  loss_rows<<<dim3(NTOK), b256, 0, stream>>>(logits, targets, rowloss);
  loss_reduce<<<dim3(1), b256, 0, stream>>>(rowloss, lossp);
  probs_rows<<<dim3(NTOK), b256, 0, stream>>>(xf, probs);

  (void)in_sizes; (void)n_in; (void)out_size; (void)ws_size;
}

// Round 9
// 1297.859 us; speedup vs baseline: 4.6184x; 1.2790x over previous
//
#include <hip/hip_runtime.h>
#include <hip/hip_bf16.h>

// Decoder forward: B=2,T=1024,D=1024,H=16(hs=64),L=2,FF=4096,V=32000
// Outputs (f32, concat): logits[N,V], loss[1], maps[L,B,H,T,T], probs[N,D]
// Round 9: weights pre-transposed+converted to bf16 ([N][K]) once per launch;
// bf16xbf16 GEMM (gemm_bb) with pure-copy staging; QKV fused (N=3072);
// M-fastest grid for B-panel reuse. lm_head uses bf16 weights if ws fits,
// else falls back to R8-style on-the-fly conversion (both correct).
#define VSZ 32000
#define DM  1024
#define TSEQ 1024
#define BB  2
#define HH  16
#define LL  2
#define FFD 4096
#define NTOK (BB*TSEQ)   // 2048

static constexpr size_t LOGITS_OFF = 0;
static constexpr size_t LOSS_OFF   = (size_t)NTOK * VSZ;
static constexpr size_t MAPS_OFF   = LOSS_OFF + 1;
static constexpr size_t PROBS_OFF  = MAPS_OFF + (size_t)LL*BB*HH*TSEQ*TSEQ;

typedef __attribute__((ext_vector_type(8))) short bf8;
typedef __attribute__((ext_vector_type(4))) float f32x4;
typedef __attribute__((ext_vector_type(4))) short short4v;

__device__ __forceinline__ short f2bf(float f) {   // RTNE f32 -> bf16 bits
  union { float f; unsigned u; } v; v.f = f;
  unsigned r = v.u + 0x7FFFu + ((v.u >> 16) & 1u);
  return (short)(r >> 16);
}

// ---------------- reductions ----------------
__device__ __forceinline__ float block_sum256(float v, float* sh) {
#pragma unroll
  for (int off = 32; off; off >>= 1) v += __shfl_down(v, off);
  int wid = threadIdx.x >> 6, lane = threadIdx.x & 63;
  if (lane == 0) sh[wid] = v;
  __syncthreads();
  v = sh[0] + sh[1] + sh[2] + sh[3];
  __syncthreads();
  return v;
}
__device__ __forceinline__ float block_max256(float v, float* sh) {
#pragma unroll
  for (int off = 32; off; off >>= 1) v = fmaxf(v, __shfl_down(v, off));
  int wid = threadIdx.x >> 6, lane = threadIdx.x & 63;
  if (lane == 0) sh[wid] = v;
  __syncthreads();
  v = fmaxf(fmaxf(sh[0], sh[1]), fmaxf(sh[2], sh[3]));
  __syncthreads();
  return v;
}

// ---------------- weight transpose+convert: W[K][N] f32 -> Wt[N][K] bf16 ----
__global__ __launch_bounds__(256) void transpose_cvt(const float* __restrict__ W,
    short* __restrict__ Wt, int K, int N) {
  __shared__ float T[64][65];
  const int n0 = blockIdx.x * 64, k0 = blockIdx.y * 64;
  const int tid = threadIdx.x;
  const int lr = tid >> 4, lc4 = (tid & 15) * 4;
#pragma unroll
  for (int p = 0; p < 4; ++p) {
    int k = lr + p * 16;
    float4 w = *(const float4*)&W[(size_t)(k0 + k) * N + n0 + lc4];
    T[k][lc4] = w.x; T[k][lc4+1] = w.y; T[k][lc4+2] = w.z; T[k][lc4+3] = w.w;
  }
  __syncthreads();
#pragma unroll
  for (int p = 0; p < 4; ++p) {
    int n = lr + p * 16;
    short4v s;
    s.x = f2bf(T[lc4  ][n]);
    s.y = f2bf(T[lc4+1][n]);
    s.z = f2bf(T[lc4+2][n]);
    s.w = f2bf(T[lc4+3][n]);
    *(short4v*)&Wt[(size_t)(n0 + n) * K + k0 + lc4] = s;
  }
}

// ---------------- embedding ----------------
__global__ __launch_bounds__(256) void embed_kernel(const int* __restrict__ idx,
    const float* __restrict__ we, const float* __restrict__ pe, float* __restrict__ x) {
  int i = blockIdx.x * 256 + threadIdx.x;
  int n = i >> 10;
  int d = i & 1023;
  int t = n & (TSEQ - 1);
  x[i] = we[(size_t)idx[n] * DM + d] + pe[(size_t)t * DM + d];
}

// ---------------- LayerNorm -> bf16 out (and optional f32 out) --------------
template<int ALSO_F32>
__global__ __launch_bounds__(256) void ln_bf(const float* __restrict__ in,
    const float* __restrict__ g, const float* __restrict__ b,
    short* __restrict__ outb, float* __restrict__ outf) {
  __shared__ float sh[4];
  int row = blockIdx.x, tid = threadIdx.x;
  const float* xr = in + (size_t)row * DM;
  float4 v = *(const float4*)&xr[tid * 4];
  float s  = v.x + v.y + v.z + v.w;
  float s2 = v.x*v.x + v.y*v.y + v.z*v.z + v.w*v.w;
  s  = block_sum256(s, sh);
  s2 = block_sum256(s2, sh);
  float mean = s * (1.0f / DM);
  float var  = s2 * (1.0f / DM) - mean * mean;
  float inv  = rsqrtf(var + 1e-5f);
  float4 gv = *(const float4*)&g[tid * 4];
  float4 bv = *(const float4*)&b[tid * 4];
  float4 o;
  o.x = (v.x - mean) * inv * gv.x + bv.x;
  o.y = (v.y - mean) * inv * gv.y + bv.y;
  o.z = (v.z - mean) * inv * gv.z + bv.z;
  o.w = (v.w - mean) * inv * gv.w + bv.w;
  short4v ob;
  ob.x = f2bf(o.x); ob.y = f2bf(o.y); ob.z = f2bf(o.z); ob.w = f2bf(o.w);
  *(short4v*)&outb[(size_t)row * DM + tid * 4] = ob;
  if (ALSO_F32)
    *(float4*)&outf[(size_t)row * DM + tid * 4] = o;
}

// ---------------- bf16 x bf16 MFMA GEMM -------------------------------------
// A bf16 [M][lda]; Bt bf16 [N][K]; C f32 (or bf16 if OUTBF) [M][Nn].
// 128x128 tile, BK=32, grid (M/128, N/128) -- M fastest => B-panel reuse.
template<int BIAS, int RES, int RELU, int OUTBF>
__global__ __launch_bounds__(256) void gemm_bb(const short* __restrict__ A, int lda,
    const short* __restrict__ Bt, const float* __restrict__ bias,
    void* __restrict__ Cv, int M, int K, int Nn) {
  __shared__ short As[128 * 40];
  __shared__ short Bs[128 * 40];
  float* Cf = (float*)Cv;
  short* Cb = (short*)Cv;
  const int tid  = threadIdx.x;
  const int bm   = blockIdx.x * 128, bn = blockIdx.y * 128;
  const int lane = tid & 63, wid = tid >> 6;
  const int wr = wid >> 1, wc = wid & 1;
  const int lr = lane & 15, lg = lane >> 4;
  const int sr = tid >> 1, sh = (tid & 1) * 16;

  f32x4 acc[4][4];
#pragma unroll
  for (int i = 0; i < 4; ++i)
#pragma unroll
    for (int j = 0; j < 4; ++j) acc[i][j] = (f32x4)0.f;

  for (int k0 = 0; k0 < K; k0 += 32) {
    const short* asrc = &A[(size_t)(bm + sr) * lda + k0 + sh];
    const short* bsrc = &Bt[(size_t)(bn + sr) * K + k0 + sh];
    *(bf8*)&As[sr * 40 + sh    ] = *(const bf8*)&asrc[0];
    *(bf8*)&As[sr * 40 + sh + 8] = *(const bf8*)&asrc[8];
    *(bf8*)&Bs[sr * 40 + sh    ] = *(const bf8*)&bsrc[0];
    *(bf8*)&Bs[sr * 40 + sh + 8] = *(const bf8*)&bsrc[8];
    __syncthreads();
    bf8 af[4], bfv[4];
#pragma unroll
    for (int i = 0; i < 4; ++i)
      af[i] = *(const bf8*)&As[(wr * 64 + i * 16 + lr) * 40 + lg * 8];
#pragma unroll
    for (int j = 0; j < 4; ++j)
      bfv[j] = *(const bf8*)&Bs[(wc * 64 + j * 16 + lr) * 40 + lg * 8];
#pragma unroll
    for (int i = 0; i < 4; ++i)
#pragma unroll
      for (int j = 0; j < 4; ++j)
        acc[i][j] = __builtin_amdgcn_mfma_f32_16x16x32_bf16(af[i], bfv[j], acc[i][j], 0, 0, 0);
    __syncthreads();
  }
#pragma unroll
  for (int i = 0; i < 4; ++i) {
#pragma unroll
    for (int v = 0; v < 4; ++v) {
      int row = bm + wr * 64 + i * 16 + lg * 4 + v;
      size_t rowb = (size_t)row * Nn;
#pragma unroll
      for (int j = 0; j < 4; ++j) {
        int col = bn + wc * 64 + j * 16 + lr;
        float val = acc[i][j][v];
        if (BIAS) val += bias[col];
        if (RES)  val += Cf[rowb + col];
        if (RELU) val = fmaxf(val, 0.f);
        if (OUTBF) Cb[rowb + col] = f2bf(val);
        else       Cf[rowb + col] = val;
      }
    }
  }
}

// ---------------- lm_head fallback: f32 A/B with on-the-fly cvt (R8 body,
// grid swapped: M fastest for B reuse) ---------------------------------------
template<int BIAS>
__global__ __launch_bounds__(256) void gemm_lm_cvt(const float* __restrict__ A,
    const float* __restrict__ Bw, const float* __restrict__ bias,
    float* __restrict__ C, int M, int K, int Nn) {
  __shared__ short As[128 * 40];
  __shared__ short Bs[128 * 40];
  const int tid  = threadIdx.x;
  const int bm   = blockIdx.x * 128, bn = blockIdx.y * 128;
  const int lane = tid & 63, wid = tid >> 6;
  const int wr = wid >> 1, wc = wid & 1;
  const int lr = lane & 15, lg = lane >> 4;
  const int sar = tid >> 3, sak = (tid & 7) * 4;
  const int sbn = tid & 127, sbk = (tid >> 7) * 16;
  f32x4 acc[4][4];
#pragma unroll
  for (int i = 0; i < 4; ++i)
#pragma unroll
    for (int j = 0; j < 4; ++j) acc[i][j] = (f32x4)0.f;
  for (int k0 = 0; k0 < K; k0 += 32) {
#pragma unroll
    for (int p = 0; p < 4; ++p) {
      int row = sar + p * 32;
      float4 a4 = *(const float4*)&A[(size_t)(bm + row) * K + k0 + sak];
      short4v s4;
      s4.x = f2bf(a4.x); s4.y = f2bf(a4.y); s4.z = f2bf(a4.z); s4.w = f2bf(a4.w);
      *(short4v*)&As[row * 40 + sak] = s4;
    }
    {
      short tmp[16];
#pragma unroll
      for (int e = 0; e < 16; ++e)
        tmp[e] = f2bf(Bw[(size_t)(k0 + sbk + e) * Nn + bn + sbn]);
      *(bf8*)&Bs[sbn * 40 + sbk    ] = *(bf8*)&tmp[0];
      *(bf8*)&Bs[sbn * 40 + sbk + 8] = *(bf8*)&tmp[8];
    }
    __syncthreads();
    bf8 af[4], bfv[4];
#pragma unroll
    for (int i = 0; i < 4; ++i)
      af[i] = *(const bf8*)&As[(wr * 64 + i * 16 + lr) * 40 + lg * 8];
#pragma unroll
    for (int j = 0; j < 4; ++j)
      bfv[j] = *(const bf8*)&Bs[(wc * 64 + j * 16 + lr) * 40 + lg * 8];
#pragma unroll
    for (int i = 0; i < 4; ++i)
#pragma unroll
      for (int j = 0; j < 4; ++j)
        acc[i][j] = __builtin_amdgcn_mfma_f32_16x16x32_bf16(af[i], bfv[j], acc[i][j], 0, 0, 0);
    __syncthreads();
  }
#pragma unroll
  for (int i = 0; i < 4; ++i) {
#pragma unroll
    for (int v = 0; v < 4; ++v) {
      int row = bm + wr * 64 + i * 16 + lg * 4 + v;
      size_t rowb = (size_t)row * Nn;
#pragma unroll
      for (int j = 0; j < 4; ++j) {
        int col = bn + wc * 64 + j * 16 + lr;
        float val = acc[i][j][v];
        if (BIAS) val += bias[col];
        C[rowb + col] = val;
      }
    }
  }
}

// ---------------- MFMA QK^T from packed qkv (stride 3072) -------------------
__global__ __launch_bounds__(256) void attn_qkt(const float* __restrict__ qkv,
    float* __restrict__ maps_l) {
  __shared__ short Qs[64 * 72];
  __shared__ short Ks[64 * 72];
  const int tid = threadIdx.x;
  const int qi = blockIdx.x;
  const int bh = blockIdx.y;
  const int b = bh >> 4, h = bh & 15;
  const int q0 = qi * 64;
  const int lane = tid & 63, wid = tid >> 6;
  const int wr = wid >> 1, wc = wid & 1;
  const int lr = lane & 15, lg = lane >> 4;
  const int sr = tid >> 2, sc = (tid & 3) * 16;
  {
    const float* src = &qkv[(size_t)(b * TSEQ + q0 + sr) * 3072 + h * 64 + sc];
    short tmp[16];
#pragma unroll
    for (int e = 0; e < 16; ++e) tmp[e] = f2bf(src[e]);
    *(bf8*)&Qs[sr * 72 + sc    ] = *(bf8*)&tmp[0];
    *(bf8*)&Qs[sr * 72 + sc + 8] = *(bf8*)&tmp[8];
  }
  float* mbase = maps_l + (size_t)bh * TSEQ * TSEQ;
  for (int kt = 0; kt <= qi; ++kt) {
    const int k0 = kt * 64;
    {
      const float* src = &qkv[(size_t)(b * TSEQ + k0 + sr) * 3072 + 1024 + h * 64 + sc];
      short tmp[16];
#pragma unroll
      for (int e = 0; e < 16; ++e) tmp[e] = f2bf(src[e]);
      *(bf8*)&Ks[sr * 72 + sc    ] = *(bf8*)&tmp[0];
      *(bf8*)&Ks[sr * 72 + sc + 8] = *(bf8*)&tmp[8];
    }
    __syncthreads();
    f32x4 acc[2][2];
#pragma unroll
    for (int i = 0; i < 2; ++i)
#pragma unroll
      for (int j = 0; j < 2; ++j) acc[i][j] = (f32x4)0.f;
#pragma unroll
    for (int ds = 0; ds < 2; ++ds) {
      bf8 af[2], bfv[2];
#pragma unroll
      for (int i = 0; i < 2; ++i)
        af[i] = *(const bf8*)&Qs[(wr * 32 + i * 16 + lr) * 72 + ds * 32 + lg * 8];
#pragma unroll
      for (int j = 0; j < 2; ++j)
        bfv[j] = *(const bf8*)&Ks[(wc * 32 + j * 16 + lr) * 72 + ds * 32 + lg * 8];
#pragma unroll
      for (int i = 0; i < 2; ++i)
#pragma unroll
        for (int j = 0; j < 2; ++j)
          acc[i][j] = __builtin_amdgcn_mfma_f32_16x16x32_bf16(af[i], bfv[j], acc[i][j], 0, 0, 0);
    }
#pragma unroll
    for (int i = 0; i < 2; ++i)
#pragma unroll
      for (int v = 0; v < 4; ++v) {
        int row = q0 + wr * 32 + i * 16 + lg * 4 + v;
#pragma unroll
        for (int j = 0; j < 2; ++j) {
          int col = k0 + wc * 32 + j * 16 + lr;
          mbase[(size_t)row * TSEQ + col] = acc[i][j][v] * 0.03125f;
        }
      }
    __syncthreads();
  }
}

// ---------------- in-place causal row softmax over maps ---------------------
__global__ __launch_bounds__(256) void attn_softmax(float* __restrict__ maps_l) {
  __shared__ float sh[4];
  const int q = blockIdx.x, bh = blockIdx.y;
  const int tid = threadIdx.x;
  float* mrow = maps_l + (size_t)bh * TSEQ * TSEQ + (size_t)q * TSEQ;
  float s[4];
#pragma unroll
  for (int i = 0; i < 4; ++i) {
    int kp = tid + i * 256;
    s[i] = (kp <= q) ? mrow[kp] : -1e30f;
  }
  float m = block_max256(fmaxf(fmaxf(s[0], s[1]), fmaxf(s[2], s[3])), sh);
  float e[4]; float ssum = 0.f;
#pragma unroll
  for (int i = 0; i < 4; ++i) {
    int kp = tid + i * 256;
    e[i] = (kp <= q) ? __expf(s[i] - m) : 0.f;
    ssum += e[i];
  }
  ssum = block_sum256(ssum, sh);
  float inv = 1.f / ssum;
#pragma unroll
  for (int i = 0; i < 4; ++i) mrow[tid + i * 256] = e[i] * inv;
}

// ---------------- att = wei @ v (V from packed qkv), bf16 out ---------------
__global__ __launch_bounds__(256) void attn_av2(const float* __restrict__ maps_l,
    const float* __restrict__ qkv, short* __restrict__ att_bf) {
  __shared__ float Vs[64][68];
  __shared__ float Ws[32][66];
  const int tid = threadIdx.x;
  const int ql = tid >> 3, dg = tid & 7;
  const int q0 = blockIdx.x * 32;
  const int bh = blockIdx.y;
  const int b = bh >> 4, h = bh & 15;
  const float* wbase = maps_l + (size_t)bh * TSEQ * TSEQ;
  const int vr = tid >> 2, vc = (tid & 3) * 16;
  const int wrow = tid >> 3, wc8 = (tid & 7) * 8;
  float4 a0 = {0,0,0,0}, a1 = {0,0,0,0};
  const int ntiles = (q0 + 32 + 63) >> 6;
  for (int kt = 0; kt < ntiles; ++kt) {
    const int kb0 = kt * 64;
#pragma unroll
    for (int e = 0; e < 4; ++e)
      *(float4*)&Vs[vr][vc + e * 4] =
        *(const float4*)&qkv[(size_t)(b * TSEQ + kb0 + vr) * 3072 + 2048 + h * 64 + vc + e * 4];
#pragma unroll
    for (int e = 0; e < 4; ++e)
      *(float2*)&Ws[wrow][wc8 + e * 2] =
        *(const float2*)&wbase[(size_t)(q0 + wrow) * TSEQ + kb0 + wc8 + e * 2];
    __syncthreads();
#pragma unroll 8
    for (int k = 0; k < 64; ++k) {
      float w = Ws[ql][k];
      float4 v0 = *(const float4*)&Vs[k][dg * 8];
      float4 v1 = *(const float4*)&Vs[k][dg * 8 + 4];
      a0.x += w * v0.x; a0.y += w * v0.y; a0.z += w * v0.z; a0.w += w * v0.w;
      a1.x += w * v1.x; a1.y += w * v1.y; a1.z += w * v1.z; a1.w += w * v1.w;
    }
    __syncthreads();
  }
  short* orow = &att_bf[(size_t)(b * TSEQ + q0 + ql) * DM + h * 64 + dg * 8];
  short4v s0, s1;
  s0.x = f2bf(a0.x); s0.y = f2bf(a0.y); s0.z = f2bf(a0.z); s0.w = f2bf(a0.w);
  s1.x = f2bf(a1.x); s1.y = f2bf(a1.y); s1.z = f2bf(a1.z); s1.w = f2bf(a1.w);
  *(short4v*)&orow[0] = s0;
  *(short4v*)&orow[4] = s1;
}

// ---------------- loss / probs ----------------------------------------------
__global__ __launch_bounds__(256) void loss_rows(const float* __restrict__ logits,
    const int* __restrict__ targets, float* __restrict__ rowloss) {
  __shared__ float sh[4];
  int row = blockIdx.x, tid = threadIdx.x;
  const float* lr = logits + (size_t)row * VSZ;
  float m = -1e30f;
  for (int i = tid; i < VSZ; i += 256) m = fmaxf(m, lr[i]);
  m = block_max256(m, sh);
  float ssum = 0.f;
  for (int i = tid; i < VSZ; i += 256) ssum += __expf(lr[i] - m);
  ssum = block_sum256(ssum, sh);
  if (tid == 0)
    rowloss[row] = m + logf(ssum) - lr[targets[row]];
}
__global__ __launch_bounds__(256) void loss_reduce(const float* __restrict__ rowloss,
    float* __restrict__ out) {
  __shared__ float sh[4];
  float s = 0.f;
  for (int i = threadIdx.x; i < NTOK; i += 256) s += rowloss[i];
  s = block_sum256(s, sh);
  if (threadIdx.x == 0) out[0] = s * (1.0f / NTOK);
}
__global__ __launch_bounds__(256) void probs_rows(const float* __restrict__ xf,
    float* __restrict__ out) {
  __shared__ float sh[4];
  int row = blockIdx.x, tid = threadIdx.x;
  const float* xr = xf + (size_t)row * DM;
  float4 v = *(const float4*)&xr[tid * 4];
  float m = block_max256(fmaxf(fmaxf(v.x, v.y), fmaxf(v.z, v.w)), sh);
  float ssum = __expf(v.x-m) + __expf(v.y-m) + __expf(v.z-m) + __expf(v.w-m);
  ssum = block_sum256(ssum, sh);
  float lg = m + logf(ssum);
  float* orow = out + (size_t)row * DM + tid * 4;
  orow[0] = v.x - lg;
  orow[1] = v.y - lg;
  orow[2] = v.z - lg;
  orow[3] = v.w - lg;
}

// ============================================================================
extern "C" void kernel_launch(void* const* d_in, const int* in_sizes, int n_in,
                              void* d_out, int out_size, void* d_ws, size_t ws_size,
                              hipStream_t stream) {
  const int*   idx      = (const int*)  d_in[0];
  const int*   targets  = (const int*)  d_in[1];
  const float* word_emb = (const float*)d_in[2];
  const float* pos_emb  = (const float*)d_in[3];
  const float* ln1_g    = (const float*)d_in[4];
  const float* ln1_b    = (const float*)d_in[5];
  const float* wq       = (const float*)d_in[6];
  const float* wk       = (const float*)d_in[7];
  const float* wv       = (const float*)d_in[8];
  const float* proj_w   = (const float*)d_in[9];
  const float* proj_b   = (const float*)d_in[10];
  const float* ln2_g    = (const float*)d_in[11];
  const float* ln2_b    = (const float*)d_in[12];
  const float* ff_w1    = (const float*)d_in[13];
  const float* ff_b1    = (const float*)d_in[14];
  const float* ff_w2    = (const float*)d_in[15];
  const float* ff_b2    = (const float*)d_in[16];
  const float* lnf_g    = (const float*)d_in[17];
  const float* lnf_b    = (const float*)d_in[18];
  const float* lm_w     = (const float*)d_in[19];
  const float* lm_b     = (const float*)d_in[20];

  float* outf   = (float*)d_out;
  float* logits = outf + LOGITS_OFF;
  float* lossp  = outf + LOSS_OFF;
  float* maps   = outf + MAPS_OFF;
  float* probs  = outf + PROBS_OFF;

  const size_t ND = (size_t)NTOK * DM;        // 2,097,152
  // ---- activation scratch in d_ws (~71.3 MB; known ws >= 84 MB) ----
  float* x    = (float*)d_ws;                 // ND f32
  float* xf   = x + ND;                       // ND f32
  float* qkvb = xf + ND;                      // NTOK*3072 f32
  float* rowloss = qkvb + (size_t)NTOK * 3072;// NTOK f32
  short* h_bf   = (short*)(rowloss + NTOK);   // ND bf16
  short* att_bf = h_bf + ND;                  // ND bf16
  short* ffh_bf = att_bf + ND;                // NTOK*FFD bf16
  short* xf_bf  = ffh_bf + (size_t)NTOK * FFD;// ND bf16
  char*  ws_end = (char*)(xf_bf + ND);
  const size_t act_bytes = (size_t)(ws_end - (char*)d_ws);
  const size_t lmwt_bytes = (size_t)VSZ * DM * sizeof(short);   // 65.5 MB
  const int lm_fast = (ws_size >= act_bytes + lmwt_bytes);
  short* lm_wt = (short*)ws_end;

  // ---- bf16 transposed layer weights in (dead) logits region (50.3 MB) ----
  const size_t PLW = (size_t)3 * DM * DM + DM * DM + (size_t)DM * FFD + (size_t)FFD * DM;
  short* wt_base = (short*)logits;
  auto layer_wt = [&](int l) { return wt_base + (size_t)l * PLW; };

  dim3 b256(256);
  // Pre-transpose+convert all weights
  for (int l = 0; l < LL; ++l) {
    short* qkvt = layer_wt(l);
    short* projt = qkvt + (size_t)3 * DM * DM;
    short* ff1t  = projt + (size_t)DM * DM;
    short* ff2t  = ff1t + (size_t)DM * FFD;
    const size_t wo = (size_t)l * DM * DM;
    transpose_cvt<<<dim3(16, 16), b256, 0, stream>>>(wq + wo, qkvt,                 DM, DM);
    transpose_cvt<<<dim3(16, 16), b256, 0, stream>>>(wk + wo, qkvt + (size_t)DM*DM, DM, DM);
    transpose_cvt<<<dim3(16, 16), b256, 0, stream>>>(wv + wo, qkvt + (size_t)2*DM*DM, DM, DM);
    transpose_cvt<<<dim3(16, 16), b256, 0, stream>>>(proj_w + wo, projt, DM, DM);
    transpose_cvt<<<dim3(FFD/64, 16), b256, 0, stream>>>(ff_w1 + (size_t)l*DM*FFD, ff1t, DM, FFD);
    transpose_cvt<<<dim3(16, FFD/64), b256, 0, stream>>>(ff_w2 + (size_t)l*FFD*DM, ff2t, FFD, DM);
  }
  if (lm_fast)
    transpose_cvt<<<dim3(VSZ/64, 16), b256, 0, stream>>>(lm_w, lm_wt, DM, VSZ);

  embed_kernel<<<dim3((NTOK * DM) / 256), b256, 0, stream>>>(idx, word_emb, pos_emb, x);

  for (int l = 0; l < LL; ++l) {
    short* qkvt = layer_wt(l);
    short* projt = qkvt + (size_t)3 * DM * DM;
    short* ff1t  = projt + (size_t)DM * DM;
    short* ff2t  = ff1t + (size_t)DM * FFD;
    ln_bf<0><<<dim3(NTOK), b256, 0, stream>>>(x, ln1_g + l * DM, ln1_b + l * DM, h_bf, nullptr);
    gemm_bb<0,0,0,0><<<dim3(NTOK/128, 3072/128), b256, 0, stream>>>(h_bf, DM, qkvt, nullptr, qkvb, NTOK, DM, 3072);
    float* maps_l = maps + (size_t)l * BB * HH * TSEQ * TSEQ;
    attn_qkt<<<dim3(TSEQ/64, BB*HH), b256, 0, stream>>>(qkvb, maps_l);
    attn_softmax<<<dim3(TSEQ, BB*HH), b256, 0, stream>>>(maps_l);
    attn_av2<<<dim3(TSEQ/32, BB*HH), b256, 0, stream>>>(maps_l, qkvb, att_bf);
    gemm_bb<1,1,0,0><<<dim3(NTOK/128, DM/128), b256, 0, stream>>>(att_bf, DM, projt, proj_b + l * DM, x, NTOK, DM, DM);
    ln_bf<0><<<dim3(NTOK), b256, 0, stream>>>(x, ln2_g + l * DM, ln2_b + l * DM, h_bf, nullptr);
    gemm_bb<1,0,1,1><<<dim3(NTOK/128, FFD/128), b256, 0, stream>>>(h_bf, DM, ff1t, ff_b1 + l * FFD, ffh_bf, NTOK, DM, FFD);
    gemm_bb<1,1,0,0><<<dim3(NTOK/128, DM/128), b256, 0, stream>>>(ffh_bf, FFD, ff2t, ff_b2 + l * DM, x, NTOK, FFD, DM);
  }

  ln_bf<1><<<dim3(NTOK), b256, 0, stream>>>(x, lnf_g, lnf_b, xf_bf, xf);
  if (lm_fast)
    gemm_bb<1,0,0,0><<<dim3(NTOK/128, VSZ/128), b256, 0, stream>>>(xf_bf, DM, lm_wt, lm_b, logits, NTOK, DM, VSZ);
  else
    gemm_lm_cvt<1><<<dim3(NTOK/128, VSZ/128), b256, 0, stream>>>(xf, lm_w, lm_b, logits, NTOK, DM, VSZ);
  loss_rows<<<dim3(NTOK), b256, 0, stream>>>(logits, targets, rowloss);
  loss_reduce<<<dim3(1), b256, 0, stream>>>(rowloss, lossp);
  probs_rows<<<dim3(NTOK), b256, 0, stream>>>(xf, probs);

  (void)in_sizes; (void)n_in; (void)out_size;
}

// Round 10
// 1219.709 us; speedup vs baseline: 4.9143x; 1.0641x over previous
//
#include <hip/hip_runtime.h>
#include <hip/hip_bf16.h>

// Decoder forward: B=2,T=1024,D=1024,H=16(hs=64),L=2,FF=4096,V=32000
// Outputs (f32, concat): logits[N,V], loss[1], maps[L,B,H,T,T], probs[N,D]
// Round 10: gemm_bb staging -> __builtin_amdgcn_global_load_lds (16B, linear
// LDS, m97 structure); 12 layer-weight transposes fused into one dispatch.
#define VSZ 32000
#define DM  1024
#define TSEQ 1024
#define BB  2
#define HH  16
#define LL  2
#define FFD 4096
#define NTOK (BB*TSEQ)   // 2048

static constexpr size_t LOGITS_OFF = 0;
static constexpr size_t LOSS_OFF   = (size_t)NTOK * VSZ;
static constexpr size_t MAPS_OFF   = LOSS_OFF + 1;
static constexpr size_t PROBS_OFF  = MAPS_OFF + (size_t)LL*BB*HH*TSEQ*TSEQ;

typedef __attribute__((ext_vector_type(8))) short bf8;
typedef __attribute__((ext_vector_type(4))) float f32x4;
typedef __attribute__((ext_vector_type(4))) short short4v;

__device__ __forceinline__ short f2bf(float f) {   // RTNE f32 -> bf16 bits
  union { float f; unsigned u; } v; v.f = f;
  unsigned r = v.u + 0x7FFFu + ((v.u >> 16) & 1u);
  return (short)(r >> 16);
}

// Async global->LDS, 16 B per lane: dest = wave-uniform base + lane*16,
// source = per-lane global address. vmcnt tracked by compiler (drained at
// __syncthreads).
__device__ __forceinline__ void gload16(const void* g, void* l) {
  __builtin_amdgcn_global_load_lds(
      (const __attribute__((address_space(1))) void*)g,
      (__attribute__((address_space(3))) void*)l, 16, 0, 0);
}

// ---------------- reductions ----------------
__device__ __forceinline__ float block_sum256(float v, float* sh) {
#pragma unroll
  for (int off = 32; off; off >>= 1) v += __shfl_down(v, off);
  int wid = threadIdx.x >> 6, lane = threadIdx.x & 63;
  if (lane == 0) sh[wid] = v;
  __syncthreads();
  v = sh[0] + sh[1] + sh[2] + sh[3];
  __syncthreads();
  return v;
}
__device__ __forceinline__ float block_max256(float v, float* sh) {
#pragma unroll
  for (int off = 32; off; off >>= 1) v = fmaxf(v, __shfl_down(v, off));
  int wid = threadIdx.x >> 6, lane = threadIdx.x & 63;
  if (lane == 0) sh[wid] = v;
  __syncthreads();
  v = fmaxf(fmaxf(sh[0], sh[1]), fmaxf(sh[2], sh[3]));
  __syncthreads();
  return v;
}

// ---------------- fused weight transpose+convert (all layer weights) --------
// W[K][N] f32 -> Wt[N][K] bf16. 64x64 tiles; block->weight map by ranges.
// Per layer: [0,256) wq, [256,512) wk, [512,768) wv, [768,1024) proj,
// [1024,2048) ff1 (N=FFD), [2048,3072) ff2 (K=FFD). 3072 blocks/layer.
static constexpr size_t PLW = (size_t)4 * DM * DM + (size_t)DM * FFD + (size_t)FFD * DM;
__global__ __launch_bounds__(256) void transpose_all(const float* __restrict__ wq,
    const float* __restrict__ wk, const float* __restrict__ wv,
    const float* __restrict__ proj_w, const float* __restrict__ ff_w1,
    const float* __restrict__ ff_w2, short* __restrict__ wt_base) {
  __shared__ float T[64][65];
  const int bid = blockIdx.x;
  const int l = bid / 3072, r = bid % 3072;
  short* qbase = wt_base + (size_t)l * PLW;
  const float* W; short* Wt; int K, N, tn, tk;
  if (r < 1024) {
    int s = r >> 8, rr = r & 255;
    W = (s == 0 ? wq : (s == 1 ? wk : (s == 2 ? wv : proj_w))) + (size_t)l * DM * DM;
    Wt = qbase + (size_t)s * DM * DM;
    K = DM; N = DM; tn = rr & 15; tk = rr >> 4;
  } else if (r < 2048) {
    int rr = r - 1024;
    W = ff_w1 + (size_t)l * DM * FFD; Wt = qbase + (size_t)4 * DM * DM;
    K = DM; N = FFD; tn = rr & 63; tk = rr >> 6;
  } else {
    int rr = r - 2048;
    W = ff_w2 + (size_t)l * FFD * DM; Wt = qbase + (size_t)4 * DM * DM + (size_t)DM * FFD;
    K = FFD; N = DM; tn = rr & 15; tk = rr >> 4;
  }
  const int n0 = tn * 64, k0 = tk * 64;
  const int tid = threadIdx.x;
  const int lr = tid >> 4, lc4 = (tid & 15) * 4;
#pragma unroll
  for (int p = 0; p < 4; ++p) {
    int k = lr + p * 16;
    float4 w = *(const float4*)&W[(size_t)(k0 + k) * N + n0 + lc4];
    T[k][lc4] = w.x; T[k][lc4+1] = w.y; T[k][lc4+2] = w.z; T[k][lc4+3] = w.w;
  }
  __syncthreads();
#pragma unroll
  for (int p = 0; p < 4; ++p) {
    int n = lr + p * 16;
    short4v s;
    s.x = f2bf(T[lc4  ][n]);
    s.y = f2bf(T[lc4+1][n]);
    s.z = f2bf(T[lc4+2][n]);
    s.w = f2bf(T[lc4+3][n]);
    *(short4v*)&Wt[(size_t)(n0 + n) * K + k0 + lc4] = s;
  }
}

// ---------------- single-weight transpose (lm_w) ----------------------------
__global__ __launch_bounds__(256) void transpose_cvt(const float* __restrict__ W,
    short* __restrict__ Wt, int K, int N) {
  __shared__ float T[64][65];
  const int n0 = blockIdx.x * 64, k0 = blockIdx.y * 64;
  const int tid = threadIdx.x;
  const int lr = tid >> 4, lc4 = (tid & 15) * 4;
#pragma unroll
  for (int p = 0; p < 4; ++p) {
    int k = lr + p * 16;
    float4 w = *(const float4*)&W[(size_t)(k0 + k) * N + n0 + lc4];
    T[k][lc4] = w.x; T[k][lc4+1] = w.y; T[k][lc4+2] = w.z; T[k][lc4+3] = w.w;
  }
  __syncthreads();
#pragma unroll
  for (int p = 0; p < 4; ++p) {
    int n = lr + p * 16;
    short4v s;
    s.x = f2bf(T[lc4  ][n]);
    s.y = f2bf(T[lc4+1][n]);
    s.z = f2bf(T[lc4+2][n]);
    s.w = f2bf(T[lc4+3][n]);
    *(short4v*)&Wt[(size_t)(n0 + n) * K + k0 + lc4] = s;
  }
}

// ---------------- embedding ----------------
__global__ __launch_bounds__(256) void embed_kernel(const int* __restrict__ idx,
    const float* __restrict__ we, const float* __restrict__ pe, float* __restrict__ x) {
  int i = blockIdx.x * 256 + threadIdx.x;
  int n = i >> 10;
  int d = i & 1023;
  int t = n & (TSEQ - 1);
  x[i] = we[(size_t)idx[n] * DM + d] + pe[(size_t)t * DM + d];
}

// ---------------- LayerNorm -> bf16 out (and optional f32 out) --------------
template<int ALSO_F32>
__global__ __launch_bounds__(256) void ln_bf(const float* __restrict__ in,
    const float* __restrict__ g, const float* __restrict__ b,
    short* __restrict__ outb, float* __restrict__ outf) {
  __shared__ float sh[4];
  int row = blockIdx.x, tid = threadIdx.x;
  const float* xr = in + (size_t)row * DM;
  float4 v = *(const float4*)&xr[tid * 4];
  float s  = v.x + v.y + v.z + v.w;
  float s2 = v.x*v.x + v.y*v.y + v.z*v.z + v.w*v.w;
  s  = block_sum256(s, sh);
  s2 = block_sum256(s2, sh);
  float mean = s * (1.0f / DM);
  float var  = s2 * (1.0f / DM) - mean * mean;
  float inv  = rsqrtf(var + 1e-5f);
  float4 gv = *(const float4*)&g[tid * 4];
  float4 bv = *(const float4*)&b[tid * 4];
  float4 o;
  o.x = (v.x - mean) * inv * gv.x + bv.x;
  o.y = (v.y - mean) * inv * gv.y + bv.y;
  o.z = (v.z - mean) * inv * gv.z + bv.z;
  o.w = (v.w - mean) * inv * gv.w + bv.w;
  short4v ob;
  ob.x = f2bf(o.x); ob.y = f2bf(o.y); ob.z = f2bf(o.z); ob.w = f2bf(o.w);
  *(short4v*)&outb[(size_t)row * DM + tid * 4] = ob;
  if (ALSO_F32)
    *(float4*)&outf[(size_t)row * DM + tid * 4] = o;
}

// ---------------- bf16 x bf16 MFMA GEMM, global_load_lds staging ------------
// A bf16 [M][lda]; Bt bf16 [N][K]; C f32 (or bf16 if OUTBF) [M][Nn].
// 128x128 tile, BK=32, linear LDS [128][32]; each wave issues 2 async 1KB
// stages per operand per K-step (m97 structure).
template<int BIAS, int RES, int RELU, int OUTBF>
__global__ __launch_bounds__(256) void gemm_bb(const short* __restrict__ A, int lda,
    const short* __restrict__ Bt, const float* __restrict__ bias,
    void* __restrict__ Cv, int M, int K, int Nn) {
  __shared__ short As[128 * 32];
  __shared__ short Bs[128 * 32];
  float* Cf = (float*)Cv;
  short* Cb = (short*)Cv;
  const int tid  = threadIdx.x;
  const int bm   = blockIdx.x * 128, bn = blockIdx.y * 128;
  const int lane = tid & 63, wid = tid >> 6;
  const int wr = wid >> 1, wc = wid & 1;
  const int lr = lane & 15, lg = lane >> 4;
  const int srow = lane >> 2;          // 0..15 within issue
  const int schunk = (lane & 3) * 8;   // k-offset in shorts (16B chunks)

  f32x4 acc[4][4];
#pragma unroll
  for (int i = 0; i < 4; ++i)
#pragma unroll
    for (int j = 0; j < 4; ++j) acc[i][j] = (f32x4)0.f;

  for (int k0 = 0; k0 < K; k0 += 32) {
#pragma unroll
    for (int t = 0; t < 2; ++t) {
      const int issue = wid * 2 + t;          // 0..7, wave-uniform
      const int row = issue * 16 + srow;      // 0..127
      gload16(&A[(size_t)(bm + row) * lda + k0 + schunk], &As[issue * 512]);
      gload16(&Bt[(size_t)(bn + row) * K  + k0 + schunk], &Bs[issue * 512]);
    }
    __syncthreads();                          // drains vmcnt, publishes LDS
    bf8 af[4], bfv[4];
#pragma unroll
    for (int i = 0; i < 4; ++i)
      af[i] = *(const bf8*)&As[(wr * 64 + i * 16 + lr) * 32 + lg * 8];
#pragma unroll
    for (int j = 0; j < 4; ++j)
      bfv[j] = *(const bf8*)&Bs[(wc * 64 + j * 16 + lr) * 32 + lg * 8];
#pragma unroll
    for (int i = 0; i < 4; ++i)
#pragma unroll
      for (int j = 0; j < 4; ++j)
        acc[i][j] = __builtin_amdgcn_mfma_f32_16x16x32_bf16(af[i], bfv[j], acc[i][j], 0, 0, 0);
    __syncthreads();                          // all reads done before re-stage
  }
#pragma unroll
  for (int i = 0; i < 4; ++i) {
#pragma unroll
    for (int v = 0; v < 4; ++v) {
      int row = bm + wr * 64 + i * 16 + lg * 4 + v;
      size_t rowb = (size_t)row * Nn;
#pragma unroll
      for (int j = 0; j < 4; ++j) {
        int col = bn + wc * 64 + j * 16 + lr;
        float val = acc[i][j][v];
        if (BIAS) val += bias[col];
        if (RES)  val += Cf[rowb + col];
        if (RELU) val = fmaxf(val, 0.f);
        if (OUTBF) Cb[rowb + col] = f2bf(val);
        else       Cf[rowb + col] = val;
      }
    }
  }
}

// ---------------- lm_head fallback (R8-style on-the-fly cvt) ----------------
template<int BIAS>
__global__ __launch_bounds__(256) void gemm_lm_cvt(const float* __restrict__ A,
    const float* __restrict__ Bw, const float* __restrict__ bias,
    float* __restrict__ C, int M, int K, int Nn) {
  __shared__ short As[128 * 40];
  __shared__ short Bs[128 * 40];
  const int tid  = threadIdx.x;
  const int bm   = blockIdx.x * 128, bn = blockIdx.y * 128;
  const int lane = tid & 63, wid = tid >> 6;
  const int wr = wid >> 1, wc = wid & 1;
  const int lr = lane & 15, lg = lane >> 4;
  const int sar = tid >> 3, sak = (tid & 7) * 4;
  const int sbn = tid & 127, sbk = (tid >> 7) * 16;
  f32x4 acc[4][4];
#pragma unroll
  for (int i = 0; i < 4; ++i)
#pragma unroll
    for (int j = 0; j < 4; ++j) acc[i][j] = (f32x4)0.f;
  for (int k0 = 0; k0 < K; k0 += 32) {
#pragma unroll
    for (int p = 0; p < 4; ++p) {
      int row = sar + p * 32;
      float4 a4 = *(const float4*)&A[(size_t)(bm + row) * K + k0 + sak];
      short4v s4;
      s4.x = f2bf(a4.x); s4.y = f2bf(a4.y); s4.z = f2bf(a4.z); s4.w = f2bf(a4.w);
      *(short4v*)&As[row * 40 + sak] = s4;
    }
    {
      short tmp[16];
#pragma unroll
      for (int e = 0; e < 16; ++e)
        tmp[e] = f2bf(Bw[(size_t)(k0 + sbk + e) * Nn + bn + sbn]);
      *(bf8*)&Bs[sbn * 40 + sbk    ] = *(bf8*)&tmp[0];
      *(bf8*)&Bs[sbn * 40 + sbk + 8] = *(bf8*)&tmp[8];
    }
    __syncthreads();
    bf8 af[4], bfv[4];
#pragma unroll
    for (int i = 0; i < 4; ++i)
      af[i] = *(const bf8*)&As[(wr * 64 + i * 16 + lr) * 40 + lg * 8];
#pragma unroll
    for (int j = 0; j < 4; ++j)
      bfv[j] = *(const bf8*)&Bs[(wc * 64 + j * 16 + lr) * 40 + lg * 8];
#pragma unroll
    for (int i = 0; i < 4; ++i)
#pragma unroll
      for (int j = 0; j < 4; ++j)
        acc[i][j] = __builtin_amdgcn_mfma_f32_16x16x32_bf16(af[i], bfv[j], acc[i][j], 0, 0, 0);
    __syncthreads();
  }
#pragma unroll
  for (int i = 0; i < 4; ++i) {
#pragma unroll
    for (int v = 0; v < 4; ++v) {
      int row = bm + wr * 64 + i * 16 + lg * 4 + v;
      size_t rowb = (size_t)row * Nn;
#pragma unroll
      for (int j = 0; j < 4; ++j) {
        int col = bn + wc * 64 + j * 16 + lr;
        float val = acc[i][j][v];
        if (BIAS) val += bias[col];
        C[rowb + col] = val;
      }
    }
  }
}

// ---------------- MFMA QK^T from packed qkv (stride 3072) -------------------
__global__ __launch_bounds__(256) void attn_qkt(const float* __restrict__ qkv,
    float* __restrict__ maps_l) {
  __shared__ short Qs[64 * 72];
  __shared__ short Ks[64 * 72];
  const int tid = threadIdx.x;
  const int qi = blockIdx.x;
  const int bh = blockIdx.y;
  const int b = bh >> 4, h = bh & 15;
  const int q0 = qi * 64;
  const int lane = tid & 63, wid = tid >> 6;
  const int wr = wid >> 1, wc = wid & 1;
  const int lr = lane & 15, lg = lane >> 4;
  const int sr = tid >> 2, sc = (tid & 3) * 16;
  {
    const float* src = &qkv[(size_t)(b * TSEQ + q0 + sr) * 3072 + h * 64 + sc];
    short tmp[16];
#pragma unroll
    for (int e = 0; e < 16; ++e) tmp[e] = f2bf(src[e]);
    *(bf8*)&Qs[sr * 72 + sc    ] = *(bf8*)&tmp[0];
    *(bf8*)&Qs[sr * 72 + sc + 8] = *(bf8*)&tmp[8];
  }
  float* mbase = maps_l + (size_t)bh * TSEQ * TSEQ;
  for (int kt = 0; kt <= qi; ++kt) {
    const int k0 = kt * 64;
    {
      const float* src = &qkv[(size_t)(b * TSEQ + k0 + sr) * 3072 + 1024 + h * 64 + sc];
      short tmp[16];
#pragma unroll
      for (int e = 0; e < 16; ++e) tmp[e] = f2bf(src[e]);
      *(bf8*)&Ks[sr * 72 + sc    ] = *(bf8*)&tmp[0];
      *(bf8*)&Ks[sr * 72 + sc + 8] = *(bf8*)&tmp[8];
    }
    __syncthreads();
    f32x4 acc[2][2];
#pragma unroll
    for (int i = 0; i < 2; ++i)
#pragma unroll
      for (int j = 0; j < 2; ++j) acc[i][j] = (f32x4)0.f;
#pragma unroll
    for (int ds = 0; ds < 2; ++ds) {
      bf8 af[2], bfv[2];
#pragma unroll
      for (int i = 0; i < 2; ++i)
        af[i] = *(const bf8*)&Qs[(wr * 32 + i * 16 + lr) * 72 + ds * 32 + lg * 8];
#pragma unroll
      for (int j = 0; j < 2; ++j)
        bfv[j] = *(const bf8*)&Ks[(wc * 32 + j * 16 + lr) * 72 + ds * 32 + lg * 8];
#pragma unroll
      for (int i = 0; i < 2; ++i)
#pragma unroll
        for (int j = 0; j < 2; ++j)
          acc[i][j] = __builtin_amdgcn_mfma_f32_16x16x32_bf16(af[i], bfv[j], acc[i][j], 0, 0, 0);
    }
#pragma unroll
    for (int i = 0; i < 2; ++i)
#pragma unroll
      for (int v = 0; v < 4; ++v) {
        int row = q0 + wr * 32 + i * 16 + lg * 4 + v;
#pragma unroll
        for (int j = 0; j < 2; ++j) {
          int col = k0 + wc * 32 + j * 16 + lr;
          mbase[(size_t)row * TSEQ + col] = acc[i][j][v] * 0.03125f;
        }
      }
    __syncthreads();
  }
}

// ---------------- in-place causal row softmax over maps ---------------------
__global__ __launch_bounds__(256) void attn_softmax(float* __restrict__ maps_l) {
  __shared__ float sh[4];
  const int q = blockIdx.x, bh = blockIdx.y;
  const int tid = threadIdx.x;
  float* mrow = maps_l + (size_t)bh * TSEQ * TSEQ + (size_t)q * TSEQ;
  float s[4];
#pragma unroll
  for (int i = 0; i < 4; ++i) {
    int kp = tid + i * 256;
    s[i] = (kp <= q) ? mrow[kp] : -1e30f;
  }
  float m = block_max256(fmaxf(fmaxf(s[0], s[1]), fmaxf(s[2], s[3])), sh);
  float e[4]; float ssum = 0.f;
#pragma unroll
  for (int i = 0; i < 4; ++i) {
    int kp = tid + i * 256;
    e[i] = (kp <= q) ? __expf(s[i] - m) : 0.f;
    ssum += e[i];
  }
  ssum = block_sum256(ssum, sh);
  float inv = 1.f / ssum;
#pragma unroll
  for (int i = 0; i < 4; ++i) mrow[tid + i * 256] = e[i] * inv;
}

// ---------------- att = wei @ v (V from packed qkv), bf16 out ---------------
__global__ __launch_bounds__(256) void attn_av2(const float* __restrict__ maps_l,
    const float* __restrict__ qkv, short* __restrict__ att_bf) {
  __shared__ float Vs[64][68];
  __shared__ float Ws[32][66];
  const int tid = threadIdx.x;
  const int ql = tid >> 3, dg = tid & 7;
  const int q0 = blockIdx.x * 32;
  const int bh = blockIdx.y;
  const int b = bh >> 4, h = bh & 15;
  const float* wbase = maps_l + (size_t)bh * TSEQ * TSEQ;
  const int vr = tid >> 2, vc = (tid & 3) * 16;
  const int wrow = tid >> 3, wc8 = (tid & 7) * 8;
  float4 a0 = {0,0,0,0}, a1 = {0,0,0,0};
  const int ntiles = (q0 + 32 + 63) >> 6;
  for (int kt = 0; kt < ntiles; ++kt) {
    const int kb0 = kt * 64;
#pragma unroll
    for (int e = 0; e < 4; ++e)
      *(float4*)&Vs[vr][vc + e * 4] =
        *(const float4*)&qkv[(size_t)(b * TSEQ + kb0 + vr) * 3072 + 2048 + h * 64 + vc + e * 4];
#pragma unroll
    for (int e = 0; e < 4; ++e)
      *(float2*)&Ws[wrow][wc8 + e * 2] =
        *(const float2*)&wbase[(size_t)(q0 + wrow) * TSEQ + kb0 + wc8 + e * 2];
    __syncthreads();
#pragma unroll 8
    for (int k = 0; k < 64; ++k) {
      float w = Ws[ql][k];
      float4 v0 = *(const float4*)&Vs[k][dg * 8];
      float4 v1 = *(const float4*)&Vs[k][dg * 8 + 4];
      a0.x += w * v0.x; a0.y += w * v0.y; a0.z += w * v0.z; a0.w += w * v0.w;
      a1.x += w * v1.x; a1.y += w * v1.y; a1.z += w * v1.z; a1.w += w * v1.w;
    }
    __syncthreads();
  }
  short* orow = &att_bf[(size_t)(b * TSEQ + q0 + ql) * DM + h * 64 + dg * 8];
  short4v s0, s1;
  s0.x = f2bf(a0.x); s0.y = f2bf(a0.y); s0.z = f2bf(a0.z); s0.w = f2bf(a0.w);
  s1.x = f2bf(a1.x); s1.y = f2bf(a1.y); s1.z = f2bf(a1.z); s1.w = f2bf(a1.w);
  *(short4v*)&orow[0] = s0;
  *(short4v*)&orow[4] = s1;
}

// ---------------- loss / probs ----------------------------------------------
__global__ __launch_bounds__(256) void loss_rows(const float* __restrict__ logits,
    const int* __restrict__ targets, float* __restrict__ rowloss) {
  __shared__ float sh[4];
  int row = blockIdx.x, tid = threadIdx.x;
  const float* lr = logits + (size_t)row * VSZ;
  float m = -1e30f;
  for (int i = tid; i < VSZ; i += 256) m = fmaxf(m, lr[i]);
  m = block_max256(m, sh);
  float ssum = 0.f;
  for (int i = tid; i < VSZ; i += 256) ssum += __expf(lr[i] - m);
  ssum = block_sum256(ssum, sh);
  if (tid == 0)
    rowloss[row] = m + logf(ssum) - lr[targets[row]];
}
__global__ __launch_bounds__(256) void loss_reduce(const float* __restrict__ rowloss,
    float* __restrict__ out) {
  __shared__ float sh[4];
  float s = 0.f;
  for (int i = threadIdx.x; i < NTOK; i += 256) s += rowloss[i];
  s = block_sum256(s, sh);
  if (threadIdx.x == 0) out[0] = s * (1.0f / NTOK);
}
__global__ __launch_bounds__(256) void probs_rows(const float* __restrict__ xf,
    float* __restrict__ out) {
  __shared__ float sh[4];
  int row = blockIdx.x, tid = threadIdx.x;
  const float* xr = xf + (size_t)row * DM;
  float4 v = *(const float4*)&xr[tid * 4];
  float m = block_max256(fmaxf(fmaxf(v.x, v.y), fmaxf(v.z, v.w)), sh);
  float ssum = __expf(v.x-m) + __expf(v.y-m) + __expf(v.z-m) + __expf(v.w-m);
  ssum = block_sum256(ssum, sh);
  float lg = m + logf(ssum);
  float* orow = out + (size_t)row * DM + tid * 4;
  orow[0] = v.x - lg;
  orow[1] = v.y - lg;
  orow[2] = v.z - lg;
  orow[3] = v.w - lg;
}

// ============================================================================
extern "C" void kernel_launch(void* const* d_in, const int* in_sizes, int n_in,
                              void* d_out, int out_size, void* d_ws, size_t ws_size,
                              hipStream_t stream) {
  const int*   idx      = (const int*)  d_in[0];
  const int*   targets  = (const int*)  d_in[1];
  const float* word_emb = (const float*)d_in[2];
  const float* pos_emb  = (const float*)d_in[3];
  const float* ln1_g    = (const float*)d_in[4];
  const float* ln1_b    = (const float*)d_in[5];
  const float* wq       = (const float*)d_in[6];
  const float* wk       = (const float*)d_in[7];
  const float* wv       = (const float*)d_in[8];
  const float* proj_w   = (const float*)d_in[9];
  const float* proj_b   = (const float*)d_in[10];
  const float* ln2_g    = (const float*)d_in[11];
  const float* ln2_b    = (const float*)d_in[12];
  const float* ff_w1    = (const float*)d_in[13];
  const float* ff_b1    = (const float*)d_in[14];
  const float* ff_w2    = (const float*)d_in[15];
  const float* ff_b2    = (const float*)d_in[16];
  const float* lnf_g    = (const float*)d_in[17];
  const float* lnf_b    = (const float*)d_in[18];
  const float* lm_w     = (const float*)d_in[19];
  const float* lm_b     = (const float*)d_in[20];

  float* outf   = (float*)d_out;
  float* logits = outf + LOGITS_OFF;
  float* lossp  = outf + LOSS_OFF;
  float* maps   = outf + MAPS_OFF;
  float* probs  = outf + PROBS_OFF;

  const size_t ND = (size_t)NTOK * DM;
  // ---- activation scratch in d_ws ----
  float* x    = (float*)d_ws;                 // ND f32
  float* xf   = x + ND;                       // ND f32
  float* qkvb = xf + ND;                      // NTOK*3072 f32
  float* rowloss = qkvb + (size_t)NTOK * 3072;// NTOK f32
  short* h_bf   = (short*)(rowloss + NTOK);   // ND bf16
  short* att_bf = h_bf + ND;                  // ND bf16
  short* ffh_bf = att_bf + ND;                // NTOK*FFD bf16
  short* xf_bf  = ffh_bf + (size_t)NTOK * FFD;// ND bf16
  char*  ws_end = (char*)(xf_bf + ND);
  const size_t act_bytes = (size_t)(ws_end - (char*)d_ws);
  const size_t lmwt_bytes = (size_t)VSZ * DM * sizeof(short);
  const int lm_fast = (ws_size >= act_bytes + lmwt_bytes);
  short* lm_wt = (short*)ws_end;

  short* wt_base = (short*)logits;            // bf16 layer weights in logits slot
  auto layer_wt = [&](int l) { return wt_base + (size_t)l * PLW; };

  dim3 b256(256);
  transpose_all<<<dim3(2 * 3072), b256, 0, stream>>>(wq, wk, wv, proj_w, ff_w1, ff_w2, wt_base);
  if (lm_fast)
    transpose_cvt<<<dim3(VSZ/64, 16), b256, 0, stream>>>(lm_w, lm_wt, DM, VSZ);

  embed_kernel<<<dim3((NTOK * DM) / 256), b256, 0, stream>>>(idx, word_emb, pos_emb, x);

  for (int l = 0; l < LL; ++l) {
    short* qkvt = layer_wt(l);
    short* projt = qkvt + (size_t)3 * DM * DM;
    short* ff1t  = projt + (size_t)DM * DM;
    short* ff2t  = ff1t + (size_t)DM * FFD;
    ln_bf<0><<<dim3(NTOK), b256, 0, stream>>>(x, ln1_g + l * DM, ln1_b + l * DM, h_bf, nullptr);
    gemm_bb<0,0,0,0><<<dim3(NTOK/128, 3072/128), b256, 0, stream>>>(h_bf, DM, qkvt, nullptr, qkvb, NTOK, DM, 3072);
    float* maps_l = maps + (size_t)l * BB * HH * TSEQ * TSEQ;
    attn_qkt<<<dim3(TSEQ/64, BB*HH), b256, 0, stream>>>(qkvb, maps_l);
    attn_softmax<<<dim3(TSEQ, BB*HH), b256, 0, stream>>>(maps_l);
    attn_av2<<<dim3(TSEQ/32, BB*HH), b256, 0, stream>>>(maps_l, qkvb, att_bf);
    gemm_bb<1,1,0,0><<<dim3(NTOK/128, DM/128), b256, 0, stream>>>(att_bf, DM, projt, proj_b + l * DM, x, NTOK, DM, DM);
    ln_bf<0><<<dim3(NTOK), b256, 0, stream>>>(x, ln2_g + l * DM, ln2_b + l * DM, h_bf, nullptr);
    gemm_bb<1,0,1,1><<<dim3(NTOK/128, FFD/128), b256, 0, stream>>>(h_bf, DM, ff1t, ff_b1 + l * FFD, ffh_bf, NTOK, DM, FFD);
    gemm_bb<1,1,0,0><<<dim3(NTOK/128, DM/128), b256, 0, stream>>>(ffh_bf, FFD, ff2t, ff_b2 + l * DM, x, NTOK, FFD, DM);
  }

  ln_bf<1><<<dim3(NTOK), b256, 0, stream>>>(x, lnf_g, lnf_b, xf_bf, xf);
  if (lm_fast)
    gemm_bb<1,0,0,0><<<dim3(NTOK/128, VSZ/128), b256, 0, stream>>>(xf_bf, DM, lm_wt, lm_b, logits, NTOK, DM, VSZ);
  else
    gemm_lm_cvt<1><<<dim3(NTOK/128, VSZ/128), b256, 0, stream>>>(xf, lm_w, lm_b, logits, NTOK, DM, VSZ);
  loss_rows<<<dim3(NTOK), b256, 0, stream>>>(logits, targets, rowloss);
  loss_reduce<<<dim3(1), b256, 0, stream>>>(rowloss, lossp);
  probs_rows<<<dim3(NTOK), b256, 0, stream>>>(xf, probs);

  (void)in_sizes; (void)n_in; (void)out_size;
}

// Round 11
// 1215.728 us; speedup vs baseline: 4.9304x; 1.0033x over previous
//
#include <hip/hip_runtime.h>
#include <hip/hip_bf16.h>

// Decoder forward: B=2,T=1024,D=1024,H=16(hs=64),L=2,FF=4096,V=32000
// Outputs (f32, concat): logits[N,V], loss[1], maps[L,B,H,T,T], probs[N,D]
// Round 11: QK^T+softmax fused (scores strip in LDS, one maps write);
// qkv GEMM emits bf16 (pure-copy attn staging, bf16 V reads in PV).
#define VSZ 32000
#define DM  1024
#define TSEQ 1024
#define BB  2
#define HH  16
#define LL  2
#define FFD 4096
#define NTOK (BB*TSEQ)   // 2048
#define QT  16           // q-rows per attn_fused block

static constexpr size_t LOGITS_OFF = 0;
static constexpr size_t LOSS_OFF   = (size_t)NTOK * VSZ;
static constexpr size_t MAPS_OFF   = LOSS_OFF + 1;
static constexpr size_t PROBS_OFF  = MAPS_OFF + (size_t)LL*BB*HH*TSEQ*TSEQ;

typedef __attribute__((ext_vector_type(8))) short bf8;
typedef __attribute__((ext_vector_type(4))) float f32x4;
typedef __attribute__((ext_vector_type(4))) short short4v;

__device__ __forceinline__ short f2bf(float f) {   // RTNE f32 -> bf16 bits
  union { float f; unsigned u; } v; v.f = f;
  unsigned r = v.u + 0x7FFFu + ((v.u >> 16) & 1u);
  return (short)(r >> 16);
}
__device__ __forceinline__ float bf2f(short s) {
  union { unsigned u; float f; } v; v.u = ((unsigned)(unsigned short)s) << 16;
  return v.f;
}

// Async global->LDS, 16 B/lane (dest = wave-uniform base + lane*16).
__device__ __forceinline__ void gload16(const void* g, void* l) {
  __builtin_amdgcn_global_load_lds(
      (const __attribute__((address_space(1))) void*)g,
      (__attribute__((address_space(3))) void*)l, 16, 0, 0);
}

// ---------------- reductions ----------------
__device__ __forceinline__ float block_sum256(float v, float* sh) {
#pragma unroll
  for (int off = 32; off; off >>= 1) v += __shfl_down(v, off);
  int wid = threadIdx.x >> 6, lane = threadIdx.x & 63;
  if (lane == 0) sh[wid] = v;
  __syncthreads();
  v = sh[0] + sh[1] + sh[2] + sh[3];
  __syncthreads();
  return v;
}
__device__ __forceinline__ float block_max256(float v, float* sh) {
#pragma unroll
  for (int off = 32; off; off >>= 1) v = fmaxf(v, __shfl_down(v, off));
  int wid = threadIdx.x >> 6, lane = threadIdx.x & 63;
  if (lane == 0) sh[wid] = v;
  __syncthreads();
  v = fmaxf(fmaxf(sh[0], sh[1]), fmaxf(sh[2], sh[3]));
  __syncthreads();
  return v;
}

// ---------------- fused weight transpose+convert (all layer weights) --------
static constexpr size_t PLW = (size_t)4 * DM * DM + (size_t)DM * FFD + (size_t)FFD * DM;
__global__ __launch_bounds__(256) void transpose_all(const float* __restrict__ wq,
    const float* __restrict__ wk, const float* __restrict__ wv,
    const float* __restrict__ proj_w, const float* __restrict__ ff_w1,
    const float* __restrict__ ff_w2, short* __restrict__ wt_base) {
  __shared__ float T[64][65];
  const int bid = blockIdx.x;
  const int l = bid / 3072, r = bid % 3072;
  short* qbase = wt_base + (size_t)l * PLW;
  const float* W; short* Wt; int K, N, tn, tk;
  if (r < 1024) {
    int s = r >> 8, rr = r & 255;
    W = (s == 0 ? wq : (s == 1 ? wk : (s == 2 ? wv : proj_w))) + (size_t)l * DM * DM;
    Wt = qbase + (size_t)s * DM * DM;
    K = DM; N = DM; tn = rr & 15; tk = rr >> 4;
  } else if (r < 2048) {
    int rr = r - 1024;
    W = ff_w1 + (size_t)l * DM * FFD; Wt = qbase + (size_t)4 * DM * DM;
    K = DM; N = FFD; tn = rr & 63; tk = rr >> 6;
  } else {
    int rr = r - 2048;
    W = ff_w2 + (size_t)l * FFD * DM; Wt = qbase + (size_t)4 * DM * DM + (size_t)DM * FFD;
    K = FFD; N = DM; tn = rr & 15; tk = rr >> 4;
  }
  const int n0 = tn * 64, k0 = tk * 64;
  const int tid = threadIdx.x;
  const int lr = tid >> 4, lc4 = (tid & 15) * 4;
#pragma unroll
  for (int p = 0; p < 4; ++p) {
    int k = lr + p * 16;
    float4 w = *(const float4*)&W[(size_t)(k0 + k) * N + n0 + lc4];
    T[k][lc4] = w.x; T[k][lc4+1] = w.y; T[k][lc4+2] = w.z; T[k][lc4+3] = w.w;
  }
  __syncthreads();
#pragma unroll
  for (int p = 0; p < 4; ++p) {
    int n = lr + p * 16;
    short4v s;
    s.x = f2bf(T[lc4  ][n]);
    s.y = f2bf(T[lc4+1][n]);
    s.z = f2bf(T[lc4+2][n]);
    s.w = f2bf(T[lc4+3][n]);
    *(short4v*)&Wt[(size_t)(n0 + n) * K + k0 + lc4] = s;
  }
}

// ---------------- single-weight transpose (lm_w) ----------------------------
__global__ __launch_bounds__(256) void transpose_cvt(const float* __restrict__ W,
    short* __restrict__ Wt, int K, int N) {
  __shared__ float T[64][65];
  const int n0 = blockIdx.x * 64, k0 = blockIdx.y * 64;
  const int tid = threadIdx.x;
  const int lr = tid >> 4, lc4 = (tid & 15) * 4;
#pragma unroll
  for (int p = 0; p < 4; ++p) {
    int k = lr + p * 16;
    float4 w = *(const float4*)&W[(size_t)(k0 + k) * N + n0 + lc4];
    T[k][lc4] = w.x; T[k][lc4+1] = w.y; T[k][lc4+2] = w.z; T[k][lc4+3] = w.w;
  }
  __syncthreads();
#pragma unroll
  for (int p = 0; p < 4; ++p) {
    int n = lr + p * 16;
    short4v s;
    s.x = f2bf(T[lc4  ][n]);
    s.y = f2bf(T[lc4+1][n]);
    s.z = f2bf(T[lc4+2][n]);
    s.w = f2bf(T[lc4+3][n]);
    *(short4v*)&Wt[(size_t)(n0 + n) * K + k0 + lc4] = s;
  }
}

// ---------------- embedding ----------------
__global__ __launch_bounds__(256) void embed_kernel(const int* __restrict__ idx,
    const float* __restrict__ we, const float* __restrict__ pe, float* __restrict__ x) {
  int i = blockIdx.x * 256 + threadIdx.x;
  int n = i >> 10;
  int d = i & 1023;
  int t = n & (TSEQ - 1);
  x[i] = we[(size_t)idx[n] * DM + d] + pe[(size_t)t * DM + d];
}

// ---------------- LayerNorm -> bf16 out (and optional f32 out) --------------
template<int ALSO_F32>
__global__ __launch_bounds__(256) void ln_bf(const float* __restrict__ in,
    const float* __restrict__ g, const float* __restrict__ b,
    short* __restrict__ outb, float* __restrict__ outf) {
  __shared__ float sh[4];
  int row = blockIdx.x, tid = threadIdx.x;
  const float* xr = in + (size_t)row * DM;
  float4 v = *(const float4*)&xr[tid * 4];
  float s  = v.x + v.y + v.z + v.w;
  float s2 = v.x*v.x + v.y*v.y + v.z*v.z + v.w*v.w;
  s  = block_sum256(s, sh);
  s2 = block_sum256(s2, sh);
  float mean = s * (1.0f / DM);
  float var  = s2 * (1.0f / DM) - mean * mean;
  float inv  = rsqrtf(var + 1e-5f);
  float4 gv = *(const float4*)&g[tid * 4];
  float4 bv = *(const float4*)&b[tid * 4];
  float4 o;
  o.x = (v.x - mean) * inv * gv.x + bv.x;
  o.y = (v.y - mean) * inv * gv.y + bv.y;
  o.z = (v.z - mean) * inv * gv.z + bv.z;
  o.w = (v.w - mean) * inv * gv.w + bv.w;
  short4v ob;
  ob.x = f2bf(o.x); ob.y = f2bf(o.y); ob.z = f2bf(o.z); ob.w = f2bf(o.w);
  *(short4v*)&outb[(size_t)row * DM + tid * 4] = ob;
  if (ALSO_F32)
    *(float4*)&outf[(size_t)row * DM + tid * 4] = o;
}

// ---------------- bf16 x bf16 MFMA GEMM, global_load_lds staging ------------
template<int BIAS, int RES, int RELU, int OUTBF>
__global__ __launch_bounds__(256) void gemm_bb(const short* __restrict__ A, int lda,
    const short* __restrict__ Bt, const float* __restrict__ bias,
    void* __restrict__ Cv, int M, int K, int Nn) {
  __shared__ short As[128 * 32];
  __shared__ short Bs[128 * 32];
  float* Cf = (float*)Cv;
  short* Cb = (short*)Cv;
  const int tid  = threadIdx.x;
  const int bm   = blockIdx.x * 128, bn = blockIdx.y * 128;
  const int lane = tid & 63, wid = tid >> 6;
  const int wr = wid >> 1, wc = wid & 1;
  const int lr = lane & 15, lg = lane >> 4;
  const int srow = lane >> 2;
  const int schunk = (lane & 3) * 8;

  f32x4 acc[4][4];
#pragma unroll
  for (int i = 0; i < 4; ++i)
#pragma unroll
    for (int j = 0; j < 4; ++j) acc[i][j] = (f32x4)0.f;

  for (int k0 = 0; k0 < K; k0 += 32) {
#pragma unroll
    for (int t = 0; t < 2; ++t) {
      const int issue = wid * 2 + t;
      const int row = issue * 16 + srow;
      gload16(&A[(size_t)(bm + row) * lda + k0 + schunk], &As[issue * 512]);
      gload16(&Bt[(size_t)(bn + row) * K  + k0 + schunk], &Bs[issue * 512]);
    }
    __syncthreads();
    bf8 af[4], bfv[4];
#pragma unroll
    for (int i = 0; i < 4; ++i)
      af[i] = *(const bf8*)&As[(wr * 64 + i * 16 + lr) * 32 + lg * 8];
#pragma unroll
    for (int j = 0; j < 4; ++j)
      bfv[j] = *(const bf8*)&Bs[(wc * 64 + j * 16 + lr) * 32 + lg * 8];
#pragma unroll
    for (int i = 0; i < 4; ++i)
#pragma unroll
      for (int j = 0; j < 4; ++j)
        acc[i][j] = __builtin_amdgcn_mfma_f32_16x16x32_bf16(af[i], bfv[j], acc[i][j], 0, 0, 0);
    __syncthreads();
  }
#pragma unroll
  for (int i = 0; i < 4; ++i) {
#pragma unroll
    for (int v = 0; v < 4; ++v) {
      int row = bm + wr * 64 + i * 16 + lg * 4 + v;
      size_t rowb = (size_t)row * Nn;
#pragma unroll
      for (int j = 0; j < 4; ++j) {
        int col = bn + wc * 64 + j * 16 + lr;
        float val = acc[i][j][v];
        if (BIAS) val += bias[col];
        if (RES)  val += Cf[rowb + col];
        if (RELU) val = fmaxf(val, 0.f);
        if (OUTBF) Cb[rowb + col] = f2bf(val);
        else       Cf[rowb + col] = val;
      }
    }
  }
}

// ---------------- lm_head fallback (on-the-fly cvt) -------------------------
template<int BIAS>
__global__ __launch_bounds__(256) void gemm_lm_cvt(const float* __restrict__ A,
    const float* __restrict__ Bw, const float* __restrict__ bias,
    float* __restrict__ C, int M, int K, int Nn) {
  __shared__ short As[128 * 40];
  __shared__ short Bs[128 * 40];
  const int tid  = threadIdx.x;
  const int bm   = blockIdx.x * 128, bn = blockIdx.y * 128;
  const int lane = tid & 63, wid = tid >> 6;
  const int wr = wid >> 1, wc = wid & 1;
  const int lr = lane & 15, lg = lane >> 4;
  const int sar = tid >> 3, sak = (tid & 7) * 4;
  const int sbn = tid & 127, sbk = (tid >> 7) * 16;
  f32x4 acc[4][4];
#pragma unroll
  for (int i = 0; i < 4; ++i)
#pragma unroll
    for (int j = 0; j < 4; ++j) acc[i][j] = (f32x4)0.f;
  for (int k0 = 0; k0 < K; k0 += 32) {
#pragma unroll
    for (int p = 0; p < 4; ++p) {
      int row = sar + p * 32;
      float4 a4 = *(const float4*)&A[(size_t)(bm + row) * K + k0 + sak];
      short4v s4;
      s4.x = f2bf(a4.x); s4.y = f2bf(a4.y); s4.z = f2bf(a4.z); s4.w = f2bf(a4.w);
      *(short4v*)&As[row * 40 + sak] = s4;
    }
    {
      short tmp[16];
#pragma unroll
      for (int e = 0; e < 16; ++e)
        tmp[e] = f2bf(Bw[(size_t)(k0 + sbk + e) * Nn + bn + sbn]);
      *(bf8*)&Bs[sbn * 40 + sbk    ] = *(bf8*)&tmp[0];
      *(bf8*)&Bs[sbn * 40 + sbk + 8] = *(bf8*)&tmp[8];
    }
    __syncthreads();
    bf8 af[4], bfv[4];
#pragma unroll
    for (int i = 0; i < 4; ++i)
      af[i] = *(const bf8*)&As[(wr * 64 + i * 16 + lr) * 40 + lg * 8];
#pragma unroll
    for (int j = 0; j < 4; ++j)
      bfv[j] = *(const bf8*)&Bs[(wc * 64 + j * 16 + lr) * 40 + lg * 8];
#pragma unroll
    for (int i = 0; i < 4; ++i)
#pragma unroll
      for (int j = 0; j < 4; ++j)
        acc[i][j] = __builtin_amdgcn_mfma_f32_16x16x32_bf16(af[i], bfv[j], acc[i][j], 0, 0, 0);
    __syncthreads();
  }
#pragma unroll
  for (int i = 0; i < 4; ++i) {
#pragma unroll
    for (int v = 0; v < 4; ++v) {
      int row = bm + wr * 64 + i * 16 + lg * 4 + v;
      size_t rowb = (size_t)row * Nn;
#pragma unroll
      for (int j = 0; j < 4; ++j) {
        int col = bn + wc * 64 + j * 16 + lr;
        float val = acc[i][j][v];
        if (BIAS) val += bias[col];
        C[rowb + col] = val;
      }
    }
  }
}

// ---------------- fused QK^T + causal softmax -> maps -----------------------
// grid (T/QT, B*H), block 256. Scores strip [QT][1024] kept in LDS; MFMA per
// 64-col k-tile (wave w owns cols w*16..w*16+15); block-local row softmax;
// single full-row write (zeros past diagonal).
__global__ __launch_bounds__(256) void attn_fused(const short* __restrict__ qkv_bf,
    float* __restrict__ maps_l) {
  __shared__ float S[QT][1032];
  __shared__ short Qs[QT * 72];
  __shared__ short Ks[64 * 72];
  const int tid = threadIdx.x;
  const int q0 = blockIdx.x * QT;
  const int bh = blockIdx.y;
  const int b = bh >> 4, h = bh & 15;
  const int lane = tid & 63, wid = tid >> 6;
  const int lr = lane & 15, lg = lane >> 4;
  if (tid < 128) {                       // stage Q: 16 rows x 64 bf16
    int r = tid >> 3, c8 = (tid & 7) * 8;
    *(bf8*)&Qs[r * 72 + c8] =
      *(const bf8*)&qkv_bf[(size_t)(b * TSEQ + q0 + r) * 3072 + h * 64 + c8];
  }
  const int ktmax = (q0 + QT - 1) / 64 + 1;
  for (int kt = 0; kt < ktmax; ++kt) {
    const int k0 = kt * 64;
    {                                    // stage K tile: 64 rows x 64 bf16
      int r = tid >> 2, c16 = (tid & 3) * 16;
      const short* src = &qkv_bf[(size_t)(b * TSEQ + k0 + r) * 3072 + 1024 + h * 64 + c16];
      *(bf8*)&Ks[r * 72 + c16    ] = *(const bf8*)&src[0];
      *(bf8*)&Ks[r * 72 + c16 + 8] = *(const bf8*)&src[8];
    }
    __syncthreads();
    f32x4 acc = (f32x4)0.f;
#pragma unroll
    for (int ds = 0; ds < 2; ++ds) {
      bf8 af  = *(const bf8*)&Qs[lr * 72 + ds * 32 + lg * 8];
      bf8 bfv = *(const bf8*)&Ks[(wid * 16 + lr) * 72 + ds * 32 + lg * 8];
      acc = __builtin_amdgcn_mfma_f32_16x16x32_bf16(af, bfv, acc, 0, 0, 0);
    }
#pragma unroll
    for (int v = 0; v < 4; ++v)
      S[lg * 4 + v][k0 + wid * 16 + lr] = acc[v] * 0.03125f;
    __syncthreads();
  }
  // row softmax: 16 rows x 16 threads each
  const int r = tid >> 4, l16 = tid & 15;
  const int qg = q0 + r;                 // valid cols 0..qg
  float m = -1e30f;
  for (int c = l16; c <= qg; c += 16) m = fmaxf(m, S[r][c]);
#pragma unroll
  for (int off = 8; off; off >>= 1) m = fmaxf(m, __shfl_xor(m, off, 16));
  float ssum = 0.f;
  for (int c = l16; c <= qg; c += 16) ssum += __expf(S[r][c] - m);
#pragma unroll
  for (int off = 8; off; off >>= 1) ssum += __shfl_xor(ssum, off, 16);
  const float inv = 1.f / ssum;
  float* mrow = maps_l + (size_t)bh * TSEQ * TSEQ + (size_t)qg * TSEQ;
  for (int c = l16; c < TSEQ; c += 16)
    mrow[c] = (c <= qg) ? __expf(S[r][c] - m) * inv : 0.f;
}

// ---------------- att = wei @ v (bf16 V from packed qkv), bf16 out ----------
__global__ __launch_bounds__(256) void attn_av2(const float* __restrict__ maps_l,
    const short* __restrict__ qkv_bf, short* __restrict__ att_bf) {
  __shared__ float Vs[64][68];
  __shared__ float Ws[32][66];
  const int tid = threadIdx.x;
  const int ql = tid >> 3, dg = tid & 7;
  const int q0 = blockIdx.x * 32;
  const int bh = blockIdx.y;
  const int b = bh >> 4, h = bh & 15;
  const float* wbase = maps_l + (size_t)bh * TSEQ * TSEQ;
  const int vr = tid >> 2, vc = (tid & 3) * 16;
  const int wrow = tid >> 3, wc8 = (tid & 7) * 8;
  float4 a0 = {0,0,0,0}, a1 = {0,0,0,0};
  const int ntiles = (q0 + 32 + 63) >> 6;
  for (int kt = 0; kt < ntiles; ++kt) {
    const int kb0 = kt * 64;
    {
      const short* src = &qkv_bf[(size_t)(b * TSEQ + kb0 + vr) * 3072 + 2048 + h * 64 + vc];
      bf8 v0 = *(const bf8*)&src[0];
      bf8 v1 = *(const bf8*)&src[8];
#pragma unroll
      for (int e = 0; e < 8; ++e) Vs[vr][vc + e]     = bf2f(v0[e]);
#pragma unroll
      for (int e = 0; e < 8; ++e) Vs[vr][vc + 8 + e] = bf2f(v1[e]);
    }
#pragma unroll
    for (int e = 0; e < 4; ++e)
      *(float2*)&Ws[wrow][wc8 + e * 2] =
        *(const float2*)&wbase[(size_t)(q0 + wrow) * TSEQ + kb0 + wc8 + e * 2];
    __syncthreads();
#pragma unroll 8
    for (int k = 0; k < 64; ++k) {
      float w = Ws[ql][k];
      float4 v0 = *(const float4*)&Vs[k][dg * 8];
      float4 v1 = *(const float4*)&Vs[k][dg * 8 + 4];
      a0.x += w * v0.x; a0.y += w * v0.y; a0.z += w * v0.z; a0.w += w * v0.w;
      a1.x += w * v1.x; a1.y += w * v1.y; a1.z += w * v1.z; a1.w += w * v1.w;
    }
    __syncthreads();
  }
  short* orow = &att_bf[(size_t)(b * TSEQ + q0 + ql) * DM + h * 64 + dg * 8];
  short4v s0, s1;
  s0.x = f2bf(a0.x); s0.y = f2bf(a0.y); s0.z = f2bf(a0.z); s0.w = f2bf(a0.w);
  s1.x = f2bf(a1.x); s1.y = f2bf(a1.y); s1.z = f2bf(a1.z); s1.w = f2bf(a1.w);
  *(short4v*)&orow[0] = s0;
  *(short4v*)&orow[4] = s1;
}

// ---------------- loss / probs ----------------------------------------------
__global__ __launch_bounds__(256) void loss_rows(const float* __restrict__ logits,
    const int* __restrict__ targets, float* __restrict__ rowloss) {
  __shared__ float sh[4];
  int row = blockIdx.x, tid = threadIdx.x;
  const float* lr = logits + (size_t)row * VSZ;
  float m = -1e30f;
  for (int i = tid; i < VSZ; i += 256) m = fmaxf(m, lr[i]);
  m = block_max256(m, sh);
  float ssum = 0.f;
  for (int i = tid; i < VSZ; i += 256) ssum += __expf(lr[i] - m);
  ssum = block_sum256(ssum, sh);
  if (tid == 0)
    rowloss[row] = m + logf(ssum) - lr[targets[row]];
}
__global__ __launch_bounds__(256) void loss_reduce(const float* __restrict__ rowloss,
    float* __restrict__ out) {
  __shared__ float sh[4];
  float s = 0.f;
  for (int i = threadIdx.x; i < NTOK; i += 256) s += rowloss[i];
  s = block_sum256(s, sh);
  if (threadIdx.x == 0) out[0] = s * (1.0f / NTOK);
}
__global__ __launch_bounds__(256) void probs_rows(const float* __restrict__ xf,
    float* __restrict__ out) {
  __shared__ float sh[4];
  int row = blockIdx.x, tid = threadIdx.x;
  const float* xr = xf + (size_t)row * DM;
  float4 v = *(const float4*)&xr[tid * 4];
  float m = block_max256(fmaxf(fmaxf(v.x, v.y), fmaxf(v.z, v.w)), sh);
  float ssum = __expf(v.x-m) + __expf(v.y-m) + __expf(v.z-m) + __expf(v.w-m);
  ssum = block_sum256(ssum, sh);
  float lg = m + logf(ssum);
  float* orow = out + (size_t)row * DM + tid * 4;
  orow[0] = v.x - lg;
  orow[1] = v.y - lg;
  orow[2] = v.z - lg;
  orow[3] = v.w - lg;
}

// ============================================================================
extern "C" void kernel_launch(void* const* d_in, const int* in_sizes, int n_in,
                              void* d_out, int out_size, void* d_ws, size_t ws_size,
                              hipStream_t stream) {
  const int*   idx      = (const int*)  d_in[0];
  const int*   targets  = (const int*)  d_in[1];
  const float* word_emb = (const float*)d_in[2];
  const float* pos_emb  = (const float*)d_in[3];
  const float* ln1_g    = (const float*)d_in[4];
  const float* ln1_b    = (const float*)d_in[5];
  const float* wq       = (const float*)d_in[6];
  const float* wk       = (const float*)d_in[7];
  const float* wv       = (const float*)d_in[8];
  const float* proj_w   = (const float*)d_in[9];
  const float* proj_b   = (const float*)d_in[10];
  const float* ln2_g    = (const float*)d_in[11];
  const float* ln2_b    = (const float*)d_in[12];
  const float* ff_w1    = (const float*)d_in[13];
  const float* ff_b1    = (const float*)d_in[14];
  const float* ff_w2    = (const float*)d_in[15];
  const float* ff_b2    = (const float*)d_in[16];
  const float* lnf_g    = (const float*)d_in[17];
  const float* lnf_b    = (const float*)d_in[18];
  const float* lm_w     = (const float*)d_in[19];
  const float* lm_b     = (const float*)d_in[20];

  float* outf   = (float*)d_out;
  float* logits = outf + LOGITS_OFF;
  float* lossp  = outf + LOSS_OFF;
  float* maps   = outf + MAPS_OFF;
  float* probs  = outf + PROBS_OFF;

  const size_t ND = (size_t)NTOK * DM;
  // ---- activation scratch in d_ws (~58 MB) ----
  float* x    = (float*)d_ws;                 // ND f32
  float* xf   = x + ND;                       // ND f32
  float* rowloss = xf + ND;                   // NTOK f32
  short* qkv_bf = (short*)(rowloss + NTOK);   // ND*3 bf16
  short* h_bf   = qkv_bf + 3 * ND;            // ND bf16
  short* att_bf = h_bf + ND;                  // ND bf16
  short* ffh_bf = att_bf + ND;                // NTOK*FFD bf16
  short* xf_bf  = ffh_bf + (size_t)NTOK * FFD;// ND bf16
  char*  ws_end = (char*)(xf_bf + ND);
  const size_t act_bytes = (size_t)(ws_end - (char*)d_ws);
  const size_t lmwt_bytes = (size_t)VSZ * DM * sizeof(short);
  const int lm_fast = (ws_size >= act_bytes + lmwt_bytes);
  short* lm_wt = (short*)ws_end;

  short* wt_base = (short*)logits;            // bf16 layer weights in logits slot
  auto layer_wt = [&](int l) { return wt_base + (size_t)l * PLW; };

  dim3 b256(256);
  transpose_all<<<dim3(2 * 3072), b256, 0, stream>>>(wq, wk, wv, proj_w, ff_w1, ff_w2, wt_base);
  if (lm_fast)
    transpose_cvt<<<dim3(VSZ/64, 16), b256, 0, stream>>>(lm_w, lm_wt, DM, VSZ);

  embed_kernel<<<dim3((NTOK * DM) / 256), b256, 0, stream>>>(idx, word_emb, pos_emb, x);

  for (int l = 0; l < LL; ++l) {
    short* qkvt = layer_wt(l);
    short* projt = qkvt + (size_t)3 * DM * DM;
    short* ff1t  = projt + (size_t)DM * DM;
    short* ff2t  = ff1t + (size_t)DM * FFD;
    ln_bf<0><<<dim3(NTOK), b256, 0, stream>>>(x, ln1_g + l * DM, ln1_b + l * DM, h_bf, nullptr);
    gemm_bb<0,0,0,1><<<dim3(NTOK/128, 3072/128), b256, 0, stream>>>(h_bf, DM, qkvt, nullptr, qkv_bf, NTOK, DM, 3072);
    float* maps_l = maps + (size_t)l * BB * HH * TSEQ * TSEQ;
    attn_fused<<<dim3(TSEQ/QT, BB*HH), b256, 0, stream>>>(qkv_bf, maps_l);
    attn_av2<<<dim3(TSEQ/32, BB*HH), b256, 0, stream>>>(maps_l, qkv_bf, att_bf);
    gemm_bb<1,1,0,0><<<dim3(NTOK/128, DM/128), b256, 0, stream>>>(att_bf, DM, projt, proj_b + l * DM, x, NTOK, DM, DM);
    ln_bf<0><<<dim3(NTOK), b256, 0, stream>>>(x, ln2_g + l * DM, ln2_b + l * DM, h_bf, nullptr);
    gemm_bb<1,0,1,1><<<dim3(NTOK/128, FFD/128), b256, 0, stream>>>(h_bf, DM, ff1t, ff_b1 + l * FFD, ffh_bf, NTOK, DM, FFD);
    gemm_bb<1,1,0,0><<<dim3(NTOK/128, DM/128), b256, 0, stream>>>(ffh_bf, FFD, ff2t, ff_b2 + l * DM, x, NTOK, FFD, DM);
  }

  ln_bf<1><<<dim3(NTOK), b256, 0, stream>>>(x, lnf_g, lnf_b, xf_bf, xf);
  if (lm_fast)
    gemm_bb<1,0,0,0><<<dim3(NTOK/128, VSZ/128), b256, 0, stream>>>(xf_bf, DM, lm_wt, lm_b, logits, NTOK, DM, VSZ);
  else
    gemm_lm_cvt<1><<<dim3(NTOK/128, VSZ/128), b256, 0, stream>>>(xf, lm_w, lm_b, logits, NTOK, DM, VSZ);
  loss_rows<<<dim3(NTOK), b256, 0, stream>>>(logits, targets, rowloss);
  loss_reduce<<<dim3(1), b256, 0, stream>>>(rowloss, lossp);
  probs_rows<<<dim3(NTOK), b256, 0, stream>>>(xf, probs);

  (void)in_sizes; (void)n_in; (void)out_size;
}

// Round 12
// 1157.843 us; speedup vs baseline: 5.1769x; 1.0500x over previous
//
#include <hip/hip_runtime.h>
#include <hip/hip_bf16.h>

// Decoder forward: B=2,T=1024,D=1024,H=16(hs=64),L=2,FF=4096,V=32000
// Outputs (f32, concat): logits[N,V], loss[1], maps[L,B,H,T,T], probs[N,D]
// Round 12: attn_fused computes PV in-kernel (attn_av2 removed); CE-loss
// partial expsums fused into lm_head GEMM epilogue (loss_rows removed);
// probs fused into final LN (probs_rows removed); XCD swizzle on lm_head.
#define VSZ 32000
#define DM  1024
#define TSEQ 1024
#define BB  2
#define HH  16
#define LL  2
#define FFD 4096
#define NTOK (BB*TSEQ)   // 2048
#define QT  16           // q-rows per attn_fused block

static constexpr size_t LOGITS_OFF = 0;
static constexpr size_t LOSS_OFF   = (size_t)NTOK * VSZ;
static constexpr size_t MAPS_OFF   = LOSS_OFF + 1;
static constexpr size_t PROBS_OFF  = MAPS_OFF + (size_t)LL*BB*HH*TSEQ*TSEQ;

typedef __attribute__((ext_vector_type(8))) short bf8;
typedef __attribute__((ext_vector_type(4))) float f32x4;
typedef __attribute__((ext_vector_type(4))) short short4v;

__device__ __forceinline__ short f2bf(float f) {   // RTNE f32 -> bf16 bits
  union { float f; unsigned u; } v; v.f = f;
  unsigned r = v.u + 0x7FFFu + ((v.u >> 16) & 1u);
  return (short)(r >> 16);
}
__device__ __forceinline__ float bf2f(short s) {
  union { unsigned u; float f; } v; v.u = ((unsigned)(unsigned short)s) << 16;
  return v.f;
}

// Async global->LDS, 16 B/lane (dest = wave-uniform base + lane*16).
__device__ __forceinline__ void gload16(const void* g, void* l) {
  __builtin_amdgcn_global_load_lds(
      (const __attribute__((address_space(1))) void*)g,
      (__attribute__((address_space(3))) void*)l, 16, 0, 0);
}

// ---------------- reductions ----------------
__device__ __forceinline__ float block_sum256(float v, float* sh) {
#pragma unroll
  for (int off = 32; off; off >>= 1) v += __shfl_down(v, off);
  int wid = threadIdx.x >> 6, lane = threadIdx.x & 63;
  if (lane == 0) sh[wid] = v;
  __syncthreads();
  v = sh[0] + sh[1] + sh[2] + sh[3];
  __syncthreads();
  return v;
}
__device__ __forceinline__ float block_max256(float v, float* sh) {
#pragma unroll
  for (int off = 32; off; off >>= 1) v = fmaxf(v, __shfl_down(v, off));
  int wid = threadIdx.x >> 6, lane = threadIdx.x & 63;
  if (lane == 0) sh[wid] = v;
  __syncthreads();
  v = fmaxf(fmaxf(sh[0], sh[1]), fmaxf(sh[2], sh[3]));
  __syncthreads();
  return v;
}

// ---------------- fused weight transpose+convert (all layer weights) --------
static constexpr size_t PLW = (size_t)4 * DM * DM + (size_t)DM * FFD + (size_t)FFD * DM;
__global__ __launch_bounds__(256) void transpose_all(const float* __restrict__ wq,
    const float* __restrict__ wk, const float* __restrict__ wv,
    const float* __restrict__ proj_w, const float* __restrict__ ff_w1,
    const float* __restrict__ ff_w2, short* __restrict__ wt_base) {
  __shared__ float T[64][65];
  const int bid = blockIdx.x;
  const int l = bid / 3072, r = bid % 3072;
  short* qbase = wt_base + (size_t)l * PLW;
  const float* W; short* Wt; int K, N, tn, tk;
  if (r < 1024) {
    int s = r >> 8, rr = r & 255;
    W = (s == 0 ? wq : (s == 1 ? wk : (s == 2 ? wv : proj_w))) + (size_t)l * DM * DM;
    Wt = qbase + (size_t)s * DM * DM;
    K = DM; N = DM; tn = rr & 15; tk = rr >> 4;
  } else if (r < 2048) {
    int rr = r - 1024;
    W = ff_w1 + (size_t)l * DM * FFD; Wt = qbase + (size_t)4 * DM * DM;
    K = DM; N = FFD; tn = rr & 63; tk = rr >> 6;
  } else {
    int rr = r - 2048;
    W = ff_w2 + (size_t)l * FFD * DM; Wt = qbase + (size_t)4 * DM * DM + (size_t)DM * FFD;
    K = FFD; N = DM; tn = rr & 15; tk = rr >> 4;
  }
  const int n0 = tn * 64, k0 = tk * 64;
  const int tid = threadIdx.x;
  const int lr = tid >> 4, lc4 = (tid & 15) * 4;
#pragma unroll
  for (int p = 0; p < 4; ++p) {
    int k = lr + p * 16;
    float4 w = *(const float4*)&W[(size_t)(k0 + k) * N + n0 + lc4];
    T[k][lc4] = w.x; T[k][lc4+1] = w.y; T[k][lc4+2] = w.z; T[k][lc4+3] = w.w;
  }
  __syncthreads();
#pragma unroll
  for (int p = 0; p < 4; ++p) {
    int n = lr + p * 16;
    short4v s;
    s.x = f2bf(T[lc4  ][n]);
    s.y = f2bf(T[lc4+1][n]);
    s.z = f2bf(T[lc4+2][n]);
    s.w = f2bf(T[lc4+3][n]);
    *(short4v*)&Wt[(size_t)(n0 + n) * K + k0 + lc4] = s;
  }
}

// ---------------- single-weight transpose (lm_w) ----------------------------
__global__ __launch_bounds__(256) void transpose_cvt(const float* __restrict__ W,
    short* __restrict__ Wt, int K, int N) {
  __shared__ float T[64][65];
  const int n0 = blockIdx.x * 64, k0 = blockIdx.y * 64;
  const int tid = threadIdx.x;
  const int lr = tid >> 4, lc4 = (tid & 15) * 4;
#pragma unroll
  for (int p = 0; p < 4; ++p) {
    int k = lr + p * 16;
    float4 w = *(const float4*)&W[(size_t)(k0 + k) * N + n0 + lc4];
    T[k][lc4] = w.x; T[k][lc4+1] = w.y; T[k][lc4+2] = w.z; T[k][lc4+3] = w.w;
  }
  __syncthreads();
#pragma unroll
  for (int p = 0; p < 4; ++p) {
    int n = lr + p * 16;
    short4v s;
    s.x = f2bf(T[lc4  ][n]);
    s.y = f2bf(T[lc4+1][n]);
    s.z = f2bf(T[lc4+2][n]);
    s.w = f2bf(T[lc4+3][n]);
    *(short4v*)&Wt[(size_t)(n0 + n) * K + k0 + lc4] = s;
  }
}

// ---------------- embedding ----------------
__global__ __launch_bounds__(256) void embed_kernel(const int* __restrict__ idx,
    const float* __restrict__ we, const float* __restrict__ pe, float* __restrict__ x) {
  int i = blockIdx.x * 256 + threadIdx.x;
  int n = i >> 10;
  int d = i & 1023;
  int t = n & (TSEQ - 1);
  x[i] = we[(size_t)idx[n] * DM + d] + pe[(size_t)t * DM + d];
}

// ---------------- LayerNorm -> bf16 out -------------------------------------
__global__ __launch_bounds__(256) void ln_bf(const float* __restrict__ in,
    const float* __restrict__ g, const float* __restrict__ b,
    short* __restrict__ outb) {
  __shared__ float sh[4];
  int row = blockIdx.x, tid = threadIdx.x;
  const float* xr = in + (size_t)row * DM;
  float4 v = *(const float4*)&xr[tid * 4];
  float s  = v.x + v.y + v.z + v.w;
  float s2 = v.x*v.x + v.y*v.y + v.z*v.z + v.w*v.w;
  s  = block_sum256(s, sh);
  s2 = block_sum256(s2, sh);
  float mean = s * (1.0f / DM);
  float var  = s2 * (1.0f / DM) - mean * mean;
  float inv  = rsqrtf(var + 1e-5f);
  float4 gv = *(const float4*)&g[tid * 4];
  float4 bv = *(const float4*)&b[tid * 4];
  float4 o;
  o.x = (v.x - mean) * inv * gv.x + bv.x;
  o.y = (v.y - mean) * inv * gv.y + bv.y;
  o.z = (v.z - mean) * inv * gv.z + bv.z;
  o.w = (v.w - mean) * inv * gv.w + bv.w;
  short4v ob;
  ob.x = f2bf(o.x); ob.y = f2bf(o.y); ob.z = f2bf(o.z); ob.w = f2bf(o.w);
  *(short4v*)&outb[(size_t)row * DM + tid * 4] = ob;
}

// ---------------- final LN -> xf_bf + probs (log_softmax over D) ------------
__global__ __launch_bounds__(256) void ln_probs(const float* __restrict__ in,
    const float* __restrict__ g, const float* __restrict__ b,
    short* __restrict__ outb, float* __restrict__ probs) {
  __shared__ float sh[4];
  int row = blockIdx.x, tid = threadIdx.x;
  const float* xr = in + (size_t)row * DM;
  float4 v = *(const float4*)&xr[tid * 4];
  float s  = v.x + v.y + v.z + v.w;
  float s2 = v.x*v.x + v.y*v.y + v.z*v.z + v.w*v.w;
  s  = block_sum256(s, sh);
  s2 = block_sum256(s2, sh);
  float mean = s * (1.0f / DM);
  float var  = s2 * (1.0f / DM) - mean * mean;
  float inv  = rsqrtf(var + 1e-5f);
  float4 gv = *(const float4*)&g[tid * 4];
  float4 bv = *(const float4*)&b[tid * 4];
  float4 o;
  o.x = (v.x - mean) * inv * gv.x + bv.x;
  o.y = (v.y - mean) * inv * gv.y + bv.y;
  o.z = (v.z - mean) * inv * gv.z + bv.z;
  o.w = (v.w - mean) * inv * gv.w + bv.w;
  short4v ob;
  ob.x = f2bf(o.x); ob.y = f2bf(o.y); ob.z = f2bf(o.z); ob.w = f2bf(o.w);
  *(short4v*)&outb[(size_t)row * DM + tid * 4] = ob;
  float m = block_max256(fmaxf(fmaxf(o.x, o.y), fmaxf(o.z, o.w)), sh);
  float ssum = __expf(o.x-m) + __expf(o.y-m) + __expf(o.z-m) + __expf(o.w-m);
  ssum = block_sum256(ssum, sh);
  float lg = m + logf(ssum);
  float* orow = probs + (size_t)row * DM + tid * 4;  // 4B-aligned only
  orow[0] = o.x - lg;
  orow[1] = o.y - lg;
  orow[2] = o.z - lg;
  orow[3] = o.w - lg;
}

// ---------------- bf16 x bf16 MFMA GEMM, global_load_lds staging ------------
// LOSSP: epilogue writes per-row partial sum(exp(val)) for this 128-col block
// into lpart[row*256 + bn/128].  SWZ: 1D grid + XCD-bijective swizzle.
template<int BIAS, int RES, int RELU, int OUTBF, int LOSSP, int SWZ>
__global__ __launch_bounds__(256) void gemm_bb(const short* __restrict__ A, int lda,
    const short* __restrict__ Bt, const float* __restrict__ bias,
    void* __restrict__ Cv, int M, int K, int Nn,
    float* __restrict__ lpart, int mblocks) {
  __shared__ short As[128 * 32];
  __shared__ short Bs[128 * 32];
  float* Cf = (float*)Cv;
  short* Cb = (short*)Cv;
  const int tid  = threadIdx.x;
  int bm, bn;
  if (SWZ) {
    const int cpx = gridDim.x >> 3;
    const int swz = (blockIdx.x & 7) * cpx + (blockIdx.x >> 3);
    bm = (swz % mblocks) * 128;
    bn = (swz / mblocks) * 128;
  } else {
    bm = blockIdx.x * 128; bn = blockIdx.y * 128;
  }
  const int lane = tid & 63, wid = tid >> 6;
  const int wr = wid >> 1, wc = wid & 1;
  const int lr = lane & 15, lg = lane >> 4;
  const int srow = lane >> 2;
  const int schunk = (lane & 3) * 8;

  f32x4 acc[4][4];
#pragma unroll
  for (int i = 0; i < 4; ++i)
#pragma unroll
    for (int j = 0; j < 4; ++j) acc[i][j] = (f32x4)0.f;

  for (int k0 = 0; k0 < K; k0 += 32) {
#pragma unroll
    for (int t = 0; t < 2; ++t) {
      const int issue = wid * 2 + t;
      const int row = issue * 16 + srow;
      gload16(&A[(size_t)(bm + row) * lda + k0 + schunk], &As[issue * 512]);
      gload16(&Bt[(size_t)(bn + row) * K  + k0 + schunk], &Bs[issue * 512]);
    }
    __syncthreads();
    bf8 af[4], bfv[4];
#pragma unroll
    for (int i = 0; i < 4; ++i)
      af[i] = *(const bf8*)&As[(wr * 64 + i * 16 + lr) * 32 + lg * 8];
#pragma unroll
    for (int j = 0; j < 4; ++j)
      bfv[j] = *(const bf8*)&Bs[(wc * 64 + j * 16 + lr) * 32 + lg * 8];
#pragma unroll
    for (int i = 0; i < 4; ++i)
#pragma unroll
      for (int j = 0; j < 4; ++j)
        acc[i][j] = __builtin_amdgcn_mfma_f32_16x16x32_bf16(af[i], bfv[j], acc[i][j], 0, 0, 0);
    __syncthreads();
  }
  float* Ls = (float*)As;   // 128 rows x 2 halves (reused after last barrier)
#pragma unroll
  for (int i = 0; i < 4; ++i) {
#pragma unroll
    for (int v = 0; v < 4; ++v) {
      int rl = wr * 64 + i * 16 + lg * 4 + v;
      size_t rowb = (size_t)(bm + rl) * Nn;
      float pe = 0.f;
#pragma unroll
      for (int j = 0; j < 4; ++j) {
        int col = bn + wc * 64 + j * 16 + lr;
        float val = acc[i][j][v];
        if (BIAS) val += bias[col];
        if (RES)  val += Cf[rowb + col];
        if (RELU) val = fmaxf(val, 0.f);
        if (OUTBF) Cb[rowb + col] = f2bf(val);
        else       Cf[rowb + col] = val;
        if (LOSSP) pe += __expf(val);
      }
      if (LOSSP) {
#pragma unroll
        for (int off = 8; off; off >>= 1) pe += __shfl_xor(pe, off);
        if (lr == 0) Ls[rl * 2 + wc] = pe;
      }
    }
  }
  if (LOSSP) {
    __syncthreads();
    if (tid < 128)
      lpart[(size_t)(bm + tid) * 256 + (bn >> 7)] = Ls[tid * 2] + Ls[tid * 2 + 1];
  }
}

// ---------------- lm_head fallback: bf16 A copy + f32 B on-the-fly cvt ------
template<int BIAS, int LOSSP, int SWZ>
__global__ __launch_bounds__(256) void gemm_lm_cvt(const short* __restrict__ A,
    const float* __restrict__ Bw, const float* __restrict__ bias,
    float* __restrict__ C, int M, int K, int Nn,
    float* __restrict__ lpart, int mblocks) {
  __shared__ short As[128 * 40];
  __shared__ short Bs[128 * 40];
  const int tid  = threadIdx.x;
  int bm, bn;
  if (SWZ) {
    const int cpx = gridDim.x >> 3;
    const int swz = (blockIdx.x & 7) * cpx + (blockIdx.x >> 3);
    bm = (swz % mblocks) * 128;
    bn = (swz / mblocks) * 128;
  } else {
    bm = blockIdx.x * 128; bn = blockIdx.y * 128;
  }
  const int lane = tid & 63, wid = tid >> 6;
  const int wr = wid >> 1, wc = wid & 1;
  const int lr = lane & 15, lg = lane >> 4;
  const int sr = tid >> 1, sh2 = (tid & 1) * 16;
  const int sbn = tid & 127, sbk = (tid >> 7) * 16;
  f32x4 acc[4][4];
#pragma unroll
  for (int i = 0; i < 4; ++i)
#pragma unroll
    for (int j = 0; j < 4; ++j) acc[i][j] = (f32x4)0.f;
  for (int k0 = 0; k0 < K; k0 += 32) {
    {
      const short* asrc = &A[(size_t)(bm + sr) * K + k0 + sh2];
      *(bf8*)&As[sr * 40 + sh2    ] = *(const bf8*)&asrc[0];
      *(bf8*)&As[sr * 40 + sh2 + 8] = *(const bf8*)&asrc[8];
    }
    {
      short tmp[16];
#pragma unroll
      for (int e = 0; e < 16; ++e)
        tmp[e] = f2bf(Bw[(size_t)(k0 + sbk + e) * Nn + bn + sbn]);
      *(bf8*)&Bs[sbn * 40 + sbk    ] = *(bf8*)&tmp[0];
      *(bf8*)&Bs[sbn * 40 + sbk + 8] = *(bf8*)&tmp[8];
    }
    __syncthreads();
    bf8 af[4], bfv[4];
#pragma unroll
    for (int i = 0; i < 4; ++i)
      af[i] = *(const bf8*)&As[(wr * 64 + i * 16 + lr) * 40 + lg * 8];
#pragma unroll
    for (int j = 0; j < 4; ++j)
      bfv[j] = *(const bf8*)&Bs[(wc * 64 + j * 16 + lr) * 40 + lg * 8];
#pragma unroll
    for (int i = 0; i < 4; ++i)
#pragma unroll
      for (int j = 0; j < 4; ++j)
        acc[i][j] = __builtin_amdgcn_mfma_f32_16x16x32_bf16(af[i], bfv[j], acc[i][j], 0, 0, 0);
    __syncthreads();
  }
  float* Ls = (float*)As;
#pragma unroll
  for (int i = 0; i < 4; ++i) {
#pragma unroll
    for (int v = 0; v < 4; ++v) {
      int rl = wr * 64 + i * 16 + lg * 4 + v;
      size_t rowb = (size_t)(bm + rl) * Nn;
      float pe = 0.f;
#pragma unroll
      for (int j = 0; j < 4; ++j) {
        int col = bn + wc * 64 + j * 16 + lr;
        float val = acc[i][j][v];
        if (BIAS) val += bias[col];
        C[rowb + col] = val;
        if (LOSSP) pe += __expf(val);
      }
      if (LOSSP) {
#pragma unroll
        for (int off = 8; off; off >>= 1) pe += __shfl_xor(pe, off);
        if (lr == 0) Ls[rl * 2 + wc] = pe;
      }
    }
  }
  if (LOSSP) {
    __syncthreads();
    if (tid < 128)
      lpart[(size_t)(bm + tid) * 256 + (bn >> 7)] = Ls[tid * 2] + Ls[tid * 2 + 1];
  }
}

// ---------------- fused QK^T + causal softmax + PV --------------------------
// grid (T/QT, B*H), block 256. Phase 1: MFMA QK^T into LDS strip S[QT][1024].
// Phase 2: row softmax; write maps row; keep normalized P in S.
// Phase 3: PV -- stage V 64-row tiles into Ks (reuse), accumulate att; write bf16.
__global__ __launch_bounds__(256) void attn_fused(const short* __restrict__ qkv_bf,
    float* __restrict__ maps_l, short* __restrict__ att_bf) {
  __shared__ float S[QT][1032];
  __shared__ short Qs[QT * 72];
  __shared__ short Ks[64 * 72];
  const int tid = threadIdx.x;
  const int q0 = blockIdx.x * QT;
  const int bh = blockIdx.y;
  const int b = bh >> 4, h = bh & 15;
  const int lane = tid & 63, wid = tid >> 6;
  const int lr = lane & 15, lg = lane >> 4;
  if (tid < 128) {                       // stage Q: 16 rows x 64 bf16
    int r = tid >> 3, c8 = (tid & 7) * 8;
    *(bf8*)&Qs[r * 72 + c8] =
      *(const bf8*)&qkv_bf[(size_t)(b * TSEQ + q0 + r) * 3072 + h * 64 + c8];
  }
  const int ktmax = (q0 + QT - 1) / 64 + 1;
  for (int kt = 0; kt < ktmax; ++kt) {
    const int k0 = kt * 64;
    {                                    // stage K tile: 64 rows x 64 bf16
      int r = tid >> 2, c16 = (tid & 3) * 16;
      const short* src = &qkv_bf[(size_t)(b * TSEQ + k0 + r) * 3072 + 1024 + h * 64 + c16];
      *(bf8*)&Ks[r * 72 + c16    ] = *(const bf8*)&src[0];
      *(bf8*)&Ks[r * 72 + c16 + 8] = *(const bf8*)&src[8];
    }
    __syncthreads();
    f32x4 acc = (f32x4)0.f;
#pragma unroll
    for (int ds = 0; ds < 2; ++ds) {
      bf8 af  = *(const bf8*)&Qs[lr * 72 + ds * 32 + lg * 8];
      bf8 bfv = *(const bf8*)&Ks[(wid * 16 + lr) * 72 + ds * 32 + lg * 8];
      acc = __builtin_amdgcn_mfma_f32_16x16x32_bf16(af, bfv, acc, 0, 0, 0);
    }
#pragma unroll
    for (int v = 0; v < 4; ++v)
      S[lg * 4 + v][k0 + wid * 16 + lr] = acc[v] * 0.03125f;
    __syncthreads();
  }
  // row softmax: 16 rows x 16 threads each; keep P in S, write maps row
  const int r = tid >> 4, l16 = tid & 15;
  const int qg = q0 + r;                 // valid cols 0..qg
  float m = -1e30f;
  for (int c = l16; c <= qg; c += 16) m = fmaxf(m, S[r][c]);
#pragma unroll
  for (int off = 8; off; off >>= 1) m = fmaxf(m, __shfl_xor(m, off, 16));
  float ssum = 0.f;
  for (int c = l16; c <= qg; c += 16) ssum += __expf(S[r][c] - m);
#pragma unroll
  for (int off = 8; off; off >>= 1) ssum += __shfl_xor(ssum, off, 16);
  const float inv = 1.f / ssum;
  float* mrow = maps_l + (size_t)bh * TSEQ * TSEQ + (size_t)qg * TSEQ;
  for (int c = l16; c < TSEQ; c += 16) {
    float p = 0.f;
    if (c <= qg) { p = __expf(S[r][c] - m) * inv; S[r][c] = p; }
    mrow[c] = p;
  }
  __syncthreads();
  // PV: thread (r,l16) owns d = l16*4..+3; V tiles staged into Ks (reuse)
  const int dbase = l16 * 4;
  float4 a = {0.f, 0.f, 0.f, 0.f};
  for (int kt = 0; kt < ktmax; ++kt) {
    const int k0 = kt * 64;
    {
      int vr2 = tid >> 2, vc2 = (tid & 3) * 16;
      const short* src = &qkv_bf[(size_t)(b * TSEQ + k0 + vr2) * 3072 + 2048 + h * 64 + vc2];
      *(bf8*)&Ks[vr2 * 72 + vc2    ] = *(const bf8*)&src[0];
      *(bf8*)&Ks[vr2 * 72 + vc2 + 8] = *(const bf8*)&src[8];
    }
    __syncthreads();
    int kend = qg - k0 + 1;
    if (kend > 64) kend = 64;
    for (int k = 0; k < kend; ++k) {
      float p = S[r][k0 + k];
      short4v vv = *(const short4v*)&Ks[k * 72 + dbase];
      a.x += p * bf2f(vv.x); a.y += p * bf2f(vv.y);
      a.z += p * bf2f(vv.z); a.w += p * bf2f(vv.w);
    }
    __syncthreads();
  }
  short* orow = &att_bf[(size_t)(b * TSEQ + qg) * DM + h * 64 + dbase];
  short4v s0;
  s0.x = f2bf(a.x); s0.y = f2bf(a.y); s0.z = f2bf(a.z); s0.w = f2bf(a.w);
  *(short4v*)orow = s0;
}

// ---------------- loss: combine partials; mean-reduce ------------------------
__global__ __launch_bounds__(256) void loss_final(const float* __restrict__ lpart,
    const float* __restrict__ logits, const int* __restrict__ targets,
    float* __restrict__ rowloss) {
  __shared__ float sh[4];
  int row = blockIdx.x, tid = threadIdx.x;
  float s = (tid < VSZ / 128) ? lpart[(size_t)row * 256 + tid] : 0.f;
  s = block_sum256(s, sh);
  if (tid == 0)
    rowloss[row] = logf(s) - logits[(size_t)row * VSZ + targets[row]];
}
__global__ __launch_bounds__(256) void loss_reduce(const float* __restrict__ rowloss,
    float* __restrict__ out) {
  __shared__ float sh[4];
  float s = 0.f;
  for (int i = threadIdx.x; i < NTOK; i += 256) s += rowloss[i];
  s = block_sum256(s, sh);
  if (threadIdx.x == 0) out[0] = s * (1.0f / NTOK);
}

// ============================================================================
extern "C" void kernel_launch(void* const* d_in, const int* in_sizes, int n_in,
                              void* d_out, int out_size, void* d_ws, size_t ws_size,
                              hipStream_t stream) {
  const int*   idx      = (const int*)  d_in[0];
  const int*   targets  = (const int*)  d_in[1];
  const float* word_emb = (const float*)d_in[2];
  const float* pos_emb  = (const float*)d_in[3];
  const float* ln1_g    = (const float*)d_in[4];
  const float* ln1_b    = (const float*)d_in[5];
  const float* wq       = (const float*)d_in[6];
  const float* wk       = (const float*)d_in[7];
  const float* wv       = (const float*)d_in[8];
  const float* proj_w   = (const float*)d_in[9];
  const float* proj_b   = (const float*)d_in[10];
  const float* ln2_g    = (const float*)d_in[11];
  const float* ln2_b    = (const float*)d_in[12];
  const float* ff_w1    = (const float*)d_in[13];
  const float* ff_b1    = (const float*)d_in[14];
  const float* ff_w2    = (const float*)d_in[15];
  const float* ff_b2    = (const float*)d_in[16];
  const float* lnf_g    = (const float*)d_in[17];
  const float* lnf_b    = (const float*)d_in[18];
  const float* lm_w     = (const float*)d_in[19];
  const float* lm_b     = (const float*)d_in[20];

  float* outf   = (float*)d_out;
  float* logits = outf + LOGITS_OFF;
  float* lossp  = outf + LOSS_OFF;
  float* maps   = outf + MAPS_OFF;
  float* probs  = outf + PROBS_OFF;

  const size_t ND = (size_t)NTOK * DM;
  // ---- activation scratch in d_ws (~52 MB) ----
  float* x    = (float*)d_ws;                 // ND f32
  float* rowloss = x + ND;                    // NTOK f32
  float* lpart   = rowloss + NTOK;            // NTOK*256 f32 (2 MB)
  short* qkv_bf = (short*)(lpart + (size_t)NTOK * 256);  // 3*ND bf16
  short* h_bf   = qkv_bf + 3 * ND;            // ND bf16
  short* att_bf = h_bf + ND;                  // ND bf16
  short* ffh_bf = att_bf + ND;                // NTOK*FFD bf16
  short* xf_bf  = ffh_bf + (size_t)NTOK * FFD;// ND bf16
  char*  ws_end = (char*)(xf_bf + ND);
  const size_t act_bytes = (size_t)(ws_end - (char*)d_ws);
  const size_t lmwt_bytes = (size_t)VSZ * DM * sizeof(short);
  const int lm_fast = (ws_size >= act_bytes + lmwt_bytes);
  short* lm_wt = (short*)ws_end;

  short* wt_base = (short*)logits;            // bf16 layer weights in logits slot
  auto layer_wt = [&](int l) { return wt_base + (size_t)l * PLW; };

  dim3 b256(256);
  transpose_all<<<dim3(2 * 3072), b256, 0, stream>>>(wq, wk, wv, proj_w, ff_w1, ff_w2, wt_base);
  if (lm_fast)
    transpose_cvt<<<dim3(VSZ/64, 16), b256, 0, stream>>>(lm_w, lm_wt, DM, VSZ);

  embed_kernel<<<dim3((NTOK * DM) / 256), b256, 0, stream>>>(idx, word_emb, pos_emb, x);

  for (int l = 0; l < LL; ++l) {
    short* qkvt = layer_wt(l);
    short* projt = qkvt + (size_t)3 * DM * DM;
    short* ff1t  = projt + (size_t)DM * DM;
    short* ff2t  = ff1t + (size_t)DM * FFD;
    ln_bf<<<dim3(NTOK), b256, 0, stream>>>(x, ln1_g + l * DM, ln1_b + l * DM, h_bf);
    gemm_bb<0,0,0,1,0,0><<<dim3(NTOK/128, 3072/128), b256, 0, stream>>>(h_bf, DM, qkvt, nullptr, qkv_bf, NTOK, DM, 3072, nullptr, 0);
    float* maps_l = maps + (size_t)l * BB * HH * TSEQ * TSEQ;
    attn_fused<<<dim3(TSEQ/QT, BB*HH), b256, 0, stream>>>(qkv_bf, maps_l, att_bf);
    gemm_bb<1,1,0,0,0,0><<<dim3(NTOK/128, DM/128), b256, 0, stream>>>(att_bf, DM, projt, proj_b + l * DM, x, NTOK, DM, DM, nullptr, 0);
    ln_bf<<<dim3(NTOK), b256, 0, stream>>>(x, ln2_g + l * DM, ln2_b + l * DM, h_bf);
    gemm_bb<1,0,1,1,0,0><<<dim3(NTOK/128, FFD/128), b256, 0, stream>>>(h_bf, DM, ff1t, ff_b1 + l * FFD, ffh_bf, NTOK, DM, FFD, nullptr, 0);
    gemm_bb<1,1,0,0,0,0><<<dim3(NTOK/128, DM/128), b256, 0, stream>>>(ffh_bf, FFD, ff2t, ff_b2 + l * DM, x, NTOK, FFD, DM, nullptr, 0);
  }

  ln_probs<<<dim3(NTOK), b256, 0, stream>>>(x, lnf_g, lnf_b, xf_bf, probs);
  const int mblocks = NTOK / 128;             // 16
  const int nwg_lm = mblocks * (VSZ / 128);   // 4000 (divisible by 8)
  if (lm_fast)
    gemm_bb<1,0,0,0,1,1><<<dim3(nwg_lm), b256, 0, stream>>>(xf_bf, DM, lm_wt, lm_b, logits, NTOK, DM, VSZ, lpart, mblocks);
  else
    gemm_lm_cvt<1,1,1><<<dim3(nwg_lm), b256, 0, stream>>>(xf_bf, lm_w, lm_b, logits, NTOK, DM, VSZ, lpart, mblocks);
  loss_final<<<dim3(NTOK), b256, 0, stream>>>(lpart, logits, targets, rowloss);
  loss_reduce<<<dim3(1), b256, 0, stream>>>(rowloss, lossp);

  (void)in_sizes; (void)n_in; (void)out_size;
}